// Round 1
// baseline (692.483 us; speedup 1.0000x reference)
//
#include <hip/hip_runtime.h>
#include <cmath>

#define BB 8
#define TT 4
#define HH 16
#define DDIM 128
#define RRDIM 64
#define CCDIM 64
#define RANKC 512
#define DMODEL 2048
#define S0C 4096
#define NQ 64      // H*T queries per batch
#define HD 2048    // H*D
#define NACT 3584  // 1024 (q) + 1024 (q_rope) + 512 (kv_down) + 1024 (k_rope)
#define SCALE_ATT 0.08838834764831845f  // 1/sqrt(128)

// ---------------- skinny GEMM: part[ks][32][NTOT(cols coloff..)] = A[32][2048] x W[2048][N], K-split 8 x 256
__global__ __launch_bounds__(256) void k_skinny(const float* __restrict__ A,
                                                const float* __restrict__ W,
                                                float* __restrict__ part,
                                                int N, int NTOT, int coloff) {
  __shared__ float a_lds[32][65];
  const int tid = threadIdx.x;
  const int ry = tid >> 6, tx = tid & 63;
  const int c0 = blockIdx.x * 64;
  const int k0 = blockIdx.y * 256;
  float acc[8] = {0.f,0.f,0.f,0.f,0.f,0.f,0.f,0.f};
  for (int kc = 0; kc < 256; kc += 64) {
    const int row = tid >> 3;
    const int kb = (tid & 7) * 8;
    const float4* s4 = reinterpret_cast<const float4*>(A + (size_t)row * DMODEL + k0 + kc + kb);
    float4 v0 = s4[0], v1 = s4[1];
    a_lds[row][kb+0]=v0.x; a_lds[row][kb+1]=v0.y; a_lds[row][kb+2]=v0.z; a_lds[row][kb+3]=v0.w;
    a_lds[row][kb+4]=v1.x; a_lds[row][kb+5]=v1.y; a_lds[row][kb+6]=v1.z; a_lds[row][kb+7]=v1.w;
    __syncthreads();
    #pragma unroll 8
    for (int kk = 0; kk < 64; ++kk) {
      float wv = W[(size_t)(k0+kc+kk) * N + c0 + tx];
      #pragma unroll
      for (int rr = 0; rr < 8; ++rr)
        acc[rr] = fmaf(a_lds[ry*8+rr][kk], wv, acc[rr]);
    }
    __syncthreads();
  }
  #pragma unroll
  for (int rr = 0; rr < 8; ++rr)
    part[((size_t)blockIdx.y * 32 + ry*8+rr) * NTOT + coloff + c0 + tx] = acc[rr];
}

// ---------------- reduce K-splits
__global__ __launch_bounds__(256) void k_reduce(const float* __restrict__ part,
                                                float* __restrict__ out, int total, int nsplit) {
  int g = blockIdx.x * 256 + threadIdx.x;
  if (g >= total) return;
  float s = 0.f;
  for (int c = 0; c < nsplit; ++c) s += part[(size_t)c * total + g];
  out[g] = s;
}

// ---------------- prep: q_lat (absorb W_up into q_content), RoPE(q_rope), RoPE(k_rope_new), copy c_kv_new
__global__ __launch_bounds__(256) void k_prep(const float* __restrict__ act,
                                              const float* __restrict__ wup,
                                              float* __restrict__ qlat,
                                              float* __restrict__ qrope,
                                              float* __restrict__ ckvn,
                                              float* __restrict__ krn) {
  int g = blockIdx.x * 256 + threadIdx.x;
  if (g < BB*NQ*RANKC) {                      // 262144: q_lat[b][qi][r]
    const int r = g & 511;
    const int qi = (g >> 9) & 63;
    const int b = g >> 15;
    const int h = qi >> 2, t = qi & 3;
    const float* arow = act + (size_t)(b*TT + t)*NACT + h*CCDIM;
    const float* wrow = wup + (size_t)r*HD + h*DDIM;
    float s = 0.f;
    #pragma unroll 8
    for (int c = 0; c < CCDIM; ++c) s = fmaf(arow[c], wrow[c], s);
    qlat[g] = s;
    return;
  }
  g -= BB*NQ*RANKC;
  if (g < BB*TT*HH*32) {                      // 16384: q_rope pairs
    const int hj = g & 31;
    const int h = (g >> 5) & 15;
    const int t = (g >> 9) & 3;
    const int b = g >> 11;
    const float* arow = act + (size_t)(b*TT + t)*NACT + 1024 + h*RRDIM;
    const float x1 = arow[hj], x2 = arow[hj+32];
    const double fr = (double)(S0C + t) * pow(10000.0, -(double)hj/32.0);
    const float cs = (float)cos(fr), sn = (float)sin(fr);
    const int qi = h*TT + t;
    qrope[((size_t)b*NQ + qi)*RRDIM + hj]      = x1*cs - x2*sn;
    qrope[((size_t)b*NQ + qi)*RRDIM + hj + 32] = x1*sn + x2*cs;
    return;
  }
  g -= BB*TT*HH*32;
  if (g < BB*TT*HH*32) {                      // 16384: k_rope_new pairs -> [b][t][h][R]
    const int hj = g & 31;
    const int h = (g >> 5) & 15;
    const int t = (g >> 9) & 3;
    const int b = g >> 11;
    const float* arow = act + (size_t)(b*TT + t)*NACT + 2560 + h*RRDIM;
    const float x1 = arow[hj], x2 = arow[hj+32];
    const double fr = (double)(S0C + t) * pow(10000.0, -(double)hj/32.0);
    const float cs = (float)cos(fr), sn = (float)sin(fr);
    krn[((size_t)(b*TT + t)*HH + h)*RRDIM + hj]      = x1*cs - x2*sn;
    krn[((size_t)(b*TT + t)*HH + h)*RRDIM + hj + 32] = x1*sn + x2*cs;
    return;
  }
  g -= BB*TT*HH*32;
  if (g < BB*TT*RANKC) {                      // 16384: c_kv_new copy
    ckvn[g] = act[(size_t)(g >> 9)*NACT + 2048 + (g & 511)];
  }
}

// ---------------- phase 1: latent flash attention partials per (b, s-chunk)
// 256 threads = 16 ty (head) x 16 tx. q rows = ty*4+i (head ty, t=i). scores K=512(content via q_lat)+64(rope).
template<int SC>
__global__ __launch_bounds__(256) void k_attn(
    const float* __restrict__ cache_ckv, const float* __restrict__ cache_kr,
    const float* __restrict__ ckvn, const float* __restrict__ krn,
    const float* __restrict__ qlat, const float* __restrict__ qrope,
    float* __restrict__ ml, float* __restrict__ olat, int NS) {
  constexpr int NJ = SC / 16;
  __shared__ float a_t[32*68];        // [kk][qi]
  __shared__ float b_t[32*136];       // [kk][s(+4 shift at 64)] / step C: [ss][r(+4 shift at 64)]
  __shared__ float qr_lds[64*68];     // [qi][j]
  __shared__ float p_t[SC*68];        // [s][qi]
  const int tid = threadIdx.x;
  const int ty = tid >> 4, tx = tid & 15;
  const int b = blockIdx.y, chunk = blockIdx.x;
  constexpr int NCC = S0C / SC;
  int scnt;
  const float *ckv, *kr;
  if (chunk < NCC) {
    scnt = SC;
    ckv = cache_ckv + ((size_t)b * S0C + (size_t)chunk * SC) * RANKC;
    kr  = cache_kr  + ((size_t)b * S0C + (size_t)chunk * SC) * (HH*RRDIM);
  } else {
    scnt = TT;
    ckv = ckvn + (size_t)b * TT * RANKC;
    kr  = krn  + (size_t)b * TT * (HH*RRDIM);
  }
  const float* qlb = qlat + (size_t)b * NQ * RANKC;
  const float* qrb = qrope + (size_t)b * NQ * RRDIM;

  { // stage q_rope -> qr_lds
    const int row = tid >> 2;
    const int jb = (tid & 3) * 16;
    const float4* s4 = reinterpret_cast<const float4*>(qrb + (size_t)row*RRDIM + jb);
    float4 v0=s4[0], v1=s4[1], v2=s4[2], v3=s4[3];
    float4* d4 = reinterpret_cast<float4*>(&qr_lds[row*68 + jb]);
    d4[0]=v0; d4[1]=v1; d4[2]=v2; d4[3]=v3;
  }

  float acc[4][NJ];
  #pragma unroll
  for (int i=0;i<4;++i)
    #pragma unroll
    for (int j=0;j<NJ;++j) acc[i][j]=0.f;

  // ---- step A: content scores = q_lat . c_kv  (K = 512, chunks of 32)
  for (int kc = 0; kc < RANKC; kc += 32) {
    { // a_t[kk][qi]
      const int row = tid >> 2;
      const int kb = (tid & 3) * 8;
      const float4* s4 = reinterpret_cast<const float4*>(qlb + (size_t)row*RANKC + kc + kb);
      float4 v0=s4[0], v1=s4[1];
      a_t[(kb+0)*68+row]=v0.x; a_t[(kb+1)*68+row]=v0.y; a_t[(kb+2)*68+row]=v0.z; a_t[(kb+3)*68+row]=v0.w;
      a_t[(kb+4)*68+row]=v1.x; a_t[(kb+5)*68+row]=v1.y; a_t[(kb+6)*68+row]=v1.z; a_t[(kb+7)*68+row]=v1.w;
    }
    if constexpr (SC == 64) {
      const int s = tid >> 2;
      const int kb = (tid & 3) * 8;
      float4 v0, v1;
      if (s < scnt) {
        const float4* s4 = reinterpret_cast<const float4*>(ckv + (size_t)s*RANKC + kc + kb);
        v0=s4[0]; v1=s4[1];
      } else { v0=make_float4(0.f,0.f,0.f,0.f); v1=v0; }
      b_t[(kb+0)*136+s]=v0.x; b_t[(kb+1)*136+s]=v0.y; b_t[(kb+2)*136+s]=v0.z; b_t[(kb+3)*136+s]=v0.w;
      b_t[(kb+4)*136+s]=v1.x; b_t[(kb+5)*136+s]=v1.y; b_t[(kb+6)*136+s]=v1.z; b_t[(kb+7)*136+s]=v1.w;
    } else {
      const int s = tid >> 1;
      const int kb = (tid & 1) * 16;
      float4 v[4];
      if (s < scnt) {
        const float4* s4 = reinterpret_cast<const float4*>(ckv + (size_t)s*RANKC + kc + kb);
        v[0]=s4[0]; v[1]=s4[1]; v[2]=s4[2]; v[3]=s4[3];
      } else { v[0]=make_float4(0.f,0.f,0.f,0.f); v[1]=v[0]; v[2]=v[0]; v[3]=v[0]; }
      const int sp = s + ((s >> 6) << 2);
      #pragma unroll
      for (int u = 0; u < 4; ++u) {
        b_t[(kb+u*4+0)*136+sp]=v[u].x; b_t[(kb+u*4+1)*136+sp]=v[u].y;
        b_t[(kb+u*4+2)*136+sp]=v[u].z; b_t[(kb+u*4+3)*136+sp]=v[u].w;
      }
    }
    __syncthreads();
    #pragma unroll 8
    for (int kk = 0; kk < 32; ++kk) {
      const float4 av = *reinterpret_cast<const float4*>(&a_t[kk*68 + ty*4]);
      const float4 b0 = *reinterpret_cast<const float4*>(&b_t[kk*136 + tx*4]);
      const float a_[4] = {av.x, av.y, av.z, av.w};
      float bv[NJ];
      bv[0]=b0.x; bv[1]=b0.y; bv[2]=b0.z; bv[3]=b0.w;
      if constexpr (SC == 128) {
        const float4 b1 = *reinterpret_cast<const float4*>(&b_t[kk*136 + 68 + tx*4]);
        bv[4]=b1.x; bv[5]=b1.y; bv[6]=b1.z; bv[7]=b1.w;
      }
      #pragma unroll
      for (int i=0;i<4;++i)
        #pragma unroll
        for (int j=0;j<NJ;++j)
          acc[i][j] = fmaf(a_[i], bv[j], acc[i][j]);
    }
    __syncthreads();
  }

  // ---- rope scores (per-head K vector, read from global/L2)
  #pragma unroll
  for (int j = 0; j < NJ; ++j) {
    const int s = (j < 4) ? (tx*4 + j) : (64 + tx*4 + (j-4));
    if (s < scnt) {
      const float* krs = kr + (size_t)s*(HH*RRDIM) + ty*RRDIM;
      #pragma unroll
      for (int jj = 0; jj < RRDIM; jj += 4) {
        const float4 kv4 = *reinterpret_cast<const float4*>(krs + jj);
        #pragma unroll
        for (int t = 0; t < 4; ++t) {
          const float4 qv4 = *reinterpret_cast<const float4*>(&qr_lds[(ty*4+t)*68 + jj]);
          acc[t][j] = fmaf(qv4.x, kv4.x, acc[t][j]);
          acc[t][j] = fmaf(qv4.y, kv4.y, acc[t][j]);
          acc[t][j] = fmaf(qv4.z, kv4.z, acc[t][j]);
          acc[t][j] = fmaf(qv4.w, kv4.w, acc[t][j]);
        }
      }
    }
  }

  // ---- partial softmax per q-row (rows live across the 16 tx lanes of each ty)
  #pragma unroll
  for (int i = 0; i < 4; ++i) {
    float mx = -1e30f;
    #pragma unroll
    for (int j = 0; j < NJ; ++j) {
      const int s = (j < 4) ? (tx*4 + j) : (64 + tx*4 + (j-4));
      float v = (s < scnt) ? acc[i][j]*SCALE_ATT : -1e30f;
      acc[i][j] = v;
      mx = fmaxf(mx, v);
    }
    #pragma unroll
    for (int off = 1; off < 16; off <<= 1) mx = fmaxf(mx, __shfl_xor(mx, off, 16));
    float sum = 0.f;
    #pragma unroll
    for (int j = 0; j < NJ; ++j) {
      const float p = __expf(acc[i][j] - mx);
      acc[i][j] = p;
      sum += p;
    }
    #pragma unroll
    for (int off = 1; off < 16; off <<= 1) sum += __shfl_xor(sum, off, 16);
    #pragma unroll
    for (int j = 0; j < NJ; ++j) {
      const int s = (j < 4) ? (tx*4 + j) : (64 + tx*4 + (j-4));
      p_t[s*68 + ty*4 + i] = acc[i][j];
    }
    if (tx == 0) {
      const size_t mb = (((size_t)b*NS + chunk)*NQ + ty*4 + i)*2;
      ml[mb] = mx; ml[mb+1] = sum;
    }
  }
  __syncthreads();

  // ---- step C: o_lat partial = P . c_kv_chunk   (64 q x 512 r, K = scnt), 4 r-quarters
  const size_t obase = ((size_t)b*NS + chunk) * NQ * RANKC;
  #pragma unroll 1
  for (int rq = 0; rq < 4; ++rq) {
    float acc2[4][8];
    #pragma unroll
    for (int i=0;i<4;++i)
      #pragma unroll
      for (int j=0;j<8;++j) acc2[i][j]=0.f;
    for (int sck = 0; sck < scnt; sck += 32) {
      __syncthreads();
      {
        const int ss = tid >> 3;
        const int cb = (tid & 7) * 16;
        const int s = sck + ss;
        float4 v[4];
        if (s < scnt) {
          const float4* s4 = reinterpret_cast<const float4*>(ckv + (size_t)s*RANKC + rq*128 + cb);
          v[0]=s4[0]; v[1]=s4[1]; v[2]=s4[2]; v[3]=s4[3];
        } else { v[0]=make_float4(0.f,0.f,0.f,0.f); v[1]=v[0]; v[2]=v[0]; v[3]=v[0]; }
        float4* d4 = reinterpret_cast<float4*>(&b_t[ss*136 + cb + ((cb >= 64) ? 4 : 0)]);
        d4[0]=v[0]; d4[1]=v[1]; d4[2]=v[2]; d4[3]=v[3];
      }
      __syncthreads();
      #pragma unroll 8
      for (int ss2 = 0; ss2 < 32; ++ss2) {
        const float4 pv = *reinterpret_cast<const float4*>(&p_t[(sck+ss2)*68 + ty*4]);
        const float4 c0 = *reinterpret_cast<const float4*>(&b_t[ss2*136 + tx*4]);
        const float4 c1 = *reinterpret_cast<const float4*>(&b_t[ss2*136 + 68 + tx*4]);
        const float p_[4] = {pv.x,pv.y,pv.z,pv.w};
        const float cv[8] = {c0.x,c0.y,c0.z,c0.w,c1.x,c1.y,c1.z,c1.w};
        #pragma unroll
        for (int i=0;i<4;++i)
          #pragma unroll
          for (int j=0;j<8;++j)
            acc2[i][j] = fmaf(p_[i], cv[j], acc2[i][j]);
      }
    }
    #pragma unroll
    for (int i=0;i<4;++i) {
      const size_t rbase = obase + (size_t)(ty*4+i)*RANKC + rq*128;
      float4 w0 = make_float4(acc2[i][0],acc2[i][1],acc2[i][2],acc2[i][3]);
      float4 w1 = make_float4(acc2[i][4],acc2[i][5],acc2[i][6],acc2[i][7]);
      *reinterpret_cast<float4*>(&olat[rbase + tx*4]) = w0;
      *reinterpret_cast<float4*>(&olat[rbase + 64 + tx*4]) = w1;
    }
  }
}

// ---------------- combine partials across chunks -> att[b][qi][512]
__global__ __launch_bounds__(256) void k_combine(const float* __restrict__ ml,
                                                 const float* __restrict__ olat,
                                                 float* __restrict__ att, int NS) {
  __shared__ float mls[130];
  const int bq = blockIdx.x;
  const int b = bq >> 6, qi = bq & 63;
  const int tid = threadIdx.x;
  for (int c = tid; c < NS*2; c += 256)
    mls[c] = ml[(((size_t)b*NS + (c>>1))*NQ + qi)*2 + (c&1)];
  __syncthreads();
  float M = -1e30f;
  for (int c = 0; c < NS; ++c) M = fmaxf(M, mls[2*c]);
  float L = 0.f;
  for (int c = 0; c < NS; ++c) L += mls[2*c+1] * __expf(mls[2*c] - M);
  const float invL = 1.0f / L;
  for (int r = tid; r < RANKC; r += 256) {
    float o = 0.f;
    for (int c = 0; c < NS; ++c)
      o += olat[(((size_t)b*NS + c)*NQ + qi)*RANKC + r] * __expf(mls[2*c] - M);
    att[(size_t)bq*RANKC + r] = o * invL;
  }
}

// ---------------- epilogue: out_head = att . W_up (per head)
__global__ __launch_bounds__(256) void k_ohead(const float* __restrict__ att,
                                               const float* __restrict__ wup,
                                               float* __restrict__ ohead) {
  const int bt = blockIdx.x >> 3;
  const int cb = (blockIdx.x & 7) * 256;
  const int b = bt >> 2, t = bt & 3;
  const int col = cb + threadIdx.x;
  const int h = col >> 7;
  const int qi = h*TT + t;
  const float* ar = att + ((size_t)b*NQ + qi)*RANKC;
  float s = 0.f;
  #pragma unroll 8
  for (int r = 0; r < RANKC; ++r)
    s = fmaf(ar[r], wup[(size_t)r*HD + col], s);
  ohead[(size_t)bt*HD + col] = s;
}

extern "C" void kernel_launch(void* const* d_in, const int* in_sizes, int n_in,
                              void* d_out, int out_size, void* d_ws, size_t ws_size,
                              hipStream_t stream) {
  const float* x     = (const float*)d_in[0];
  const float* cckv  = (const float*)d_in[1];
  const float* ckr   = (const float*)d_in[2];
  const float* w_q   = (const float*)d_in[3];
  const float* w_qr  = (const float*)d_in[4];
  const float* w_kvd = (const float*)d_in[5];
  const float* w_kvu = (const float*)d_in[6];
  const float* w_kr  = (const float*)d_in[7];
  const float* w_out = (const float*)d_in[8];
  float* out = (float*)d_out;
  float* ws = (float*)d_ws;

  // pick S-chunk size by workspace budget
  const size_t need65 = 19334144ull * sizeof(float);   // ~77.3 MB
  int NS, SC;
  if (ws_size >= need65) { NS = 65; SC = 64; }
  else                   { NS = 33; SC = 128; }

  size_t off = 0;
  float* part0 = ws + off; off += 8ull*32*NACT;                 // 917504
  float* act   = ws + off; off += 32ull*NACT;                   // 114688
  float* qlat  = ws + off; off += (size_t)BB*NQ*RANKC;          // 262144
  float* qrope = ws + off; off += (size_t)BB*NQ*RRDIM;          // 32768
  float* ckvn  = ws + off; off += (size_t)BB*TT*RANKC;          // 16384
  float* krn   = ws + off; off += (size_t)BB*TT*HH*RRDIM;       // 32768
  float* mlb   = ws + off; off += (size_t)BB*NS*NQ*2;
  float* olat  = ws + off; off += (size_t)BB*NS*NQ*RANKC;
  float* att   = ws + off; off += (size_t)BB*NQ*RANKC;          // 262144
  float* ohead = ws + off; off += 32ull*HD;                     // 65536
  float* part3 = ws + off; off += 8ull*32*HD;                   // 524288

  // phase 0: x projections (K-split skinny GEMMs into one activation buffer)
  k_skinny<<<dim3(16, 8), 256, 0, stream>>>(x, w_q,   part0, 1024, NACT, 0);
  k_skinny<<<dim3(16, 8), 256, 0, stream>>>(x, w_qr,  part0, 1024, NACT, 1024);
  k_skinny<<<dim3(8,  8), 256, 0, stream>>>(x, w_kvd, part0, 512,  NACT, 2048);
  k_skinny<<<dim3(16, 8), 256, 0, stream>>>(x, w_kr,  part0, 1024, NACT, 2560);
  k_reduce<<<dim3(448), 256, 0, stream>>>(part0, act, 32*NACT, 8);
  k_prep<<<dim3(1216), 256, 0, stream>>>(act, w_kvu, qlat, qrope, ckvn, krn);

  // phase 1: latent attention partials
  if (SC == 64)
    k_attn<64><<<dim3(NS, BB), 256, 0, stream>>>(cckv, ckr, ckvn, krn, qlat, qrope, mlb, olat, NS);
  else
    k_attn<128><<<dim3(NS, BB), 256, 0, stream>>>(cckv, ckr, ckvn, krn, qlat, qrope, mlb, olat, NS);

  // phase 2: combine + epilogues
  k_combine<<<dim3(BB*NQ), 256, 0, stream>>>(mlb, olat, att, NS);
  k_ohead<<<dim3(256), 256, 0, stream>>>(att, w_kvu, ohead);
  k_skinny<<<dim3(32, 8), 256, 0, stream>>>(ohead, w_out, part3, 2048, 2048, 0);
  k_reduce<<<dim3(256), 256, 0, stream>>>(part3, out, 32*HD, 8);
}

// Round 2
// 411.745 us; speedup vs baseline: 1.6818x; 1.6818x over previous
//
#include <hip/hip_runtime.h>
#include <cmath>

#define BB 8
#define TT 4
#define HH 16
#define DDIM 128
#define RRDIM 64
#define CCDIM 64
#define RANKC 512
#define DMODEL 2048
#define S0C 4096
#define NQ 64      // H*T queries per batch
#define HD 2048    // H*D
#define NACT 3584  // 1024 (q) + 1024 (q_rope) + 512 (kv_down) + 1024 (k_rope)
#define NSC 65     // 64 cache chunks of 64 + 1 new-token chunk
#define SCC 64
#define SCALE_ATT 0.08838834764831845f  // 1/sqrt(128)

// padded LDS index for k_proj A-tile: stride 132 + per-4-row shift (conflict-free broadcast reads)
#define AIDX(row, kk) ((row)*132 + (((row)>>2)<<2) + (kk))

// ---------------- generic skinny GEMM: part[ks][32][NTOT@coloff] += A[32][2048] x W[2048][N]
// grid (N/128, 16), 256 threads. K=128 per k-split.
__global__ __launch_bounds__(256) void k_proj(const float* __restrict__ A,
                                              const float* __restrict__ W,
                                              float* __restrict__ part,
                                              int N, int NTOT, int coloff) {
  __shared__ float a_lds[4352];
  const int tid = threadIdx.x;
  const int c0 = blockIdx.x * 128;
  const int k0 = blockIdx.y * 128;
  { // stage A[32][k0..k0+127]
    const int row = tid >> 3;
    const int kseg = (tid & 7) * 16;
    const float4* s4 = reinterpret_cast<const float4*>(A + (size_t)row * DMODEL + k0 + kseg);
    float4 v0 = s4[0], v1 = s4[1], v2 = s4[2], v3 = s4[3];
    *reinterpret_cast<float4*>(&a_lds[AIDX(row, kseg)])      = v0;
    *reinterpret_cast<float4*>(&a_lds[AIDX(row, kseg + 4)])  = v1;
    *reinterpret_cast<float4*>(&a_lds[AIDX(row, kseg + 8)])  = v2;
    *reinterpret_cast<float4*>(&a_lds[AIDX(row, kseg + 12)]) = v3;
  }
  __syncthreads();
  const int cg = tid & 31;          // col group (4 cols)
  const int rg = tid >> 5;          // row group (4 rows)
  float acc[4][4];
  #pragma unroll
  for (int r = 0; r < 4; ++r)
    #pragma unroll
    for (int c = 0; c < 4; ++c) acc[r][c] = 0.f;
  #pragma unroll 4
  for (int kk = 0; kk < 128; ++kk) {
    const float4 w4 = *reinterpret_cast<const float4*>(W + (size_t)(k0 + kk) * N + c0 + cg * 4);
    const float wv[4] = {w4.x, w4.y, w4.z, w4.w};
    #pragma unroll
    for (int r = 0; r < 4; ++r) {
      const float av = a_lds[AIDX(rg * 4 + r, kk)];
      #pragma unroll
      for (int c = 0; c < 4; ++c) acc[r][c] = fmaf(av, wv[c], acc[r][c]);
    }
  }
  #pragma unroll
  for (int r = 0; r < 4; ++r) {
    float4 o = make_float4(acc[r][0], acc[r][1], acc[r][2], acc[r][3]);
    *reinterpret_cast<float4*>(part + ((size_t)blockIdx.y * 32 + rg * 4 + r) * NTOT + coloff + c0 + cg * 4) = o;
  }
}

// ---------------- reduce K-splits
__global__ __launch_bounds__(256) void k_reduce(const float* __restrict__ part,
                                                float* __restrict__ out, int total, int nsplit) {
  int g = blockIdx.x * 256 + threadIdx.x;
  if (g >= total) return;
  float s = 0.f;
  #pragma unroll 4
  for (int c = 0; c < nsplit; ++c) s += part[(size_t)c * total + g];
  out[g] = s;
}

// ---------------- q_lat = per-head (q_content x W_up[:, h*128:h*128+64]^T), coalesced via LDS transpose
// grid (16 h, 4 r-blocks of 128), 256 threads
__global__ __launch_bounds__(256) void k_qlat(const float* __restrict__ act,
                                              const float* __restrict__ wup,
                                              float* __restrict__ qlat) {
  __shared__ float wt[64 * 132];     // [c][r]
  __shared__ float a_s[32 * 68];     // [bt][c]
  const int tid = threadIdx.x;
  const int h = blockIdx.x;
  const int r0 = blockIdx.y * 128;
  { // stage wup[r0..r0+127][h*128 .. +63] transposed
    const int r = tid >> 1;
    const int cseg = (tid & 1) * 32;
    const float* src = wup + (size_t)(r0 + r) * HD + h * DDIM + cseg;
    #pragma unroll
    for (int u = 0; u < 8; ++u) {
      const float4 v = *reinterpret_cast<const float4*>(src + u * 4);
      wt[(cseg + u * 4 + 0) * 132 + r] = v.x;
      wt[(cseg + u * 4 + 1) * 132 + r] = v.y;
      wt[(cseg + u * 4 + 2) * 132 + r] = v.z;
      wt[(cseg + u * 4 + 3) * 132 + r] = v.w;
    }
  }
  { // stage q_content slice: act[bt][h*64 .. +63]
    const int bt = tid >> 3;
    const int cseg = (tid & 7) * 8;
    const float4* s4 = reinterpret_cast<const float4*>(act + (size_t)bt * NACT + h * CCDIM + cseg);
    float4 v0 = s4[0], v1 = s4[1];
    *reinterpret_cast<float4*>(&a_s[bt * 68 + cseg])     = v0;
    *reinterpret_cast<float4*>(&a_s[bt * 68 + cseg + 4]) = v1;
  }
  __syncthreads();
  const int r = tid & 127;
  const int bth = tid >> 7;   // 0/1 -> bt 0..15 / 16..31
  float acc[16];
  #pragma unroll
  for (int i = 0; i < 16; ++i) acc[i] = 0.f;
  #pragma unroll 8
  for (int c = 0; c < 64; ++c) {
    const float wv = wt[c * 132 + r];
    #pragma unroll
    for (int i = 0; i < 16; ++i)
      acc[i] = fmaf(a_s[(bth * 16 + i) * 68 + c], wv, acc[i]);
  }
  #pragma unroll
  for (int i = 0; i < 16; ++i) {
    const int bt = bth * 16 + i;
    const int b = bt >> 2, t = bt & 3;
    qlat[((size_t)(b * NQ) + h * TT + t) * RANKC + r0 + r] = acc[i];
  }
}

// ---------------- RoPE for q_rope / k_rope_new + c_kv_new copy
__global__ __launch_bounds__(256) void k_rope(const float* __restrict__ act,
                                              float* __restrict__ qrope,
                                              float* __restrict__ ckvn,
                                              float* __restrict__ krn) {
  int g = blockIdx.x * 256 + threadIdx.x;
  if (g < BB * TT * HH * 32) {                  // q_rope pairs
    const int hj = g & 31;
    const int h = (g >> 5) & 15;
    const int t = (g >> 9) & 3;
    const int b = g >> 11;
    const float* arow = act + (size_t)(b * TT + t) * NACT + 1024 + h * RRDIM;
    const float x1 = arow[hj], x2 = arow[hj + 32];
    const double fr = (double)(S0C + t) * pow(10000.0, -(double)hj / 32.0);
    const float cs = (float)cos(fr), sn = (float)sin(fr);
    const int qi = h * TT + t;
    qrope[((size_t)b * NQ + qi) * RRDIM + hj]      = x1 * cs - x2 * sn;
    qrope[((size_t)b * NQ + qi) * RRDIM + hj + 32] = x1 * sn + x2 * cs;
    return;
  }
  g -= BB * TT * HH * 32;
  if (g < BB * TT * HH * 32) {                  // k_rope_new pairs -> [b][t][h][R]
    const int hj = g & 31;
    const int h = (g >> 5) & 15;
    const int t = (g >> 9) & 3;
    const int b = g >> 11;
    const float* arow = act + (size_t)(b * TT + t) * NACT + 2560 + h * RRDIM;
    const float x1 = arow[hj], x2 = arow[hj + 32];
    const double fr = (double)(S0C + t) * pow(10000.0, -(double)hj / 32.0);
    const float cs = (float)cos(fr), sn = (float)sin(fr);
    krn[((size_t)(b * TT + t) * HH + h) * RRDIM + hj]      = x1 * cs - x2 * sn;
    krn[((size_t)(b * TT + t) * HH + h) * RRDIM + hj + 32] = x1 * sn + x2 * cs;
    return;
  }
  g -= BB * TT * HH * 32;
  if (g < BB * TT * RANKC) {                    // c_kv_new copy
    ckvn[g] = act[(size_t)(g >> 9) * NACT + 2048 + (g & 511)];
  }
}

// ---------------- phase 1: latent flash attention partials per (b, s-chunk), SC=64
// 256 thr = 16 ty (head) x 16 tx.
__global__ __launch_bounds__(256, 4) void k_attn(
    const float* __restrict__ cache_ckv, const float* __restrict__ cache_kr,
    const float* __restrict__ ckvn, const float* __restrict__ krn,
    const float* __restrict__ qlat, const float* __restrict__ qrope,
    float* __restrict__ ml, float* __restrict__ olat) {
  __shared__ float a_t[32 * 68];     // [kk][qi]
  __shared__ float b_t[32 * 68];     // [kk][s]
  __shared__ float p_t[64 * 68];     // [s][qi]
  const int tid = threadIdx.x;
  const int ty = tid >> 4, tx = tid & 15;
  const int b = blockIdx.y, chunk = blockIdx.x;
  int scnt;
  const float *ckv, *kr;
  if (chunk < 64) {
    scnt = SCC;
    ckv = cache_ckv + ((size_t)b * S0C + (size_t)chunk * SCC) * RANKC;
    kr  = cache_kr  + ((size_t)b * S0C + (size_t)chunk * SCC) * (HH * RRDIM);
  } else {
    scnt = TT;
    ckv = ckvn + (size_t)b * TT * RANKC;
    kr  = krn  + (size_t)b * TT * (HH * RRDIM);
  }
  const float* qlb = qlat + (size_t)b * NQ * RANKC;
  const float* qrb = qrope + (size_t)b * NQ * RRDIM;

  float acc[4][4];
  #pragma unroll
  for (int i = 0; i < 4; ++i)
    #pragma unroll
    for (int j = 0; j < 4; ++j) acc[i][j] = 0.f;

  // ---- step A: content scores = q_lat . c_kv (K=512, chunks of 32)
  for (int kc = 0; kc < RANKC; kc += 32) {
    { // a_t[kk][qi]
      const int row = tid >> 2;
      const int kb = (tid & 3) * 8;
      const float4* s4 = reinterpret_cast<const float4*>(qlb + (size_t)row * RANKC + kc + kb);
      float4 v0 = s4[0], v1 = s4[1];
      a_t[(kb+0)*68+row]=v0.x; a_t[(kb+1)*68+row]=v0.y; a_t[(kb+2)*68+row]=v0.z; a_t[(kb+3)*68+row]=v0.w;
      a_t[(kb+4)*68+row]=v1.x; a_t[(kb+5)*68+row]=v1.y; a_t[(kb+6)*68+row]=v1.z; a_t[(kb+7)*68+row]=v1.w;
    }
    { // b_t[kk][s]
      const int s = tid >> 2;
      const int kb = (tid & 3) * 8;
      float4 v0, v1;
      if (s < scnt) {
        const float4* s4 = reinterpret_cast<const float4*>(ckv + (size_t)s * RANKC + kc + kb);
        v0 = s4[0]; v1 = s4[1];
      } else { v0 = make_float4(0.f,0.f,0.f,0.f); v1 = v0; }
      b_t[(kb+0)*68+s]=v0.x; b_t[(kb+1)*68+s]=v0.y; b_t[(kb+2)*68+s]=v0.z; b_t[(kb+3)*68+s]=v0.w;
      b_t[(kb+4)*68+s]=v1.x; b_t[(kb+5)*68+s]=v1.y; b_t[(kb+6)*68+s]=v1.z; b_t[(kb+7)*68+s]=v1.w;
    }
    __syncthreads();
    #pragma unroll 8
    for (int kk = 0; kk < 32; ++kk) {
      const float4 av = *reinterpret_cast<const float4*>(&a_t[kk * 68 + ty * 4]);
      const float4 bv = *reinterpret_cast<const float4*>(&b_t[kk * 68 + tx * 4]);
      const float a_[4] = {av.x, av.y, av.z, av.w};
      const float b_[4] = {bv.x, bv.y, bv.z, bv.w};
      #pragma unroll
      for (int i = 0; i < 4; ++i)
        #pragma unroll
        for (int j = 0; j < 4; ++j)
          acc[i][j] = fmaf(a_[i], b_[j], acc[i][j]);
    }
    __syncthreads();
  }

  // ---- rope scores: register-blocked; q_rope reads are L1-broadcast (same addr across tx lanes)
  #pragma unroll 4
  for (int jj = 0; jj < RRDIM; jj += 4) {
    float4 qv[4];
    #pragma unroll
    for (int i = 0; i < 4; ++i)
      qv[i] = *reinterpret_cast<const float4*>(qrb + (size_t)(ty * 4 + i) * RRDIM + jj);
    #pragma unroll
    for (int j = 0; j < 4; ++j) {
      const int s = tx * 4 + j;
      if (s < scnt) {
        const float4 kv = *reinterpret_cast<const float4*>(kr + (size_t)s * (HH * RRDIM) + ty * RRDIM + jj);
        #pragma unroll
        for (int i = 0; i < 4; ++i) {
          acc[i][j] = fmaf(qv[i].x, kv.x, acc[i][j]);
          acc[i][j] = fmaf(qv[i].y, kv.y, acc[i][j]);
          acc[i][j] = fmaf(qv[i].z, kv.z, acc[i][j]);
          acc[i][j] = fmaf(qv[i].w, kv.w, acc[i][j]);
        }
      }
    }
  }

  // ---- partial softmax per q-row (row spread over the 16 tx lanes)
  #pragma unroll
  for (int i = 0; i < 4; ++i) {
    float mx = -1e30f;
    #pragma unroll
    for (int j = 0; j < 4; ++j) {
      const int s = tx * 4 + j;
      float v = (s < scnt) ? acc[i][j] * SCALE_ATT : -1e30f;
      acc[i][j] = v;
      mx = fmaxf(mx, v);
    }
    #pragma unroll
    for (int off = 1; off < 16; off <<= 1) mx = fmaxf(mx, __shfl_xor(mx, off, 16));
    float sum = 0.f;
    #pragma unroll
    for (int j = 0; j < 4; ++j) {
      const float p = __expf(acc[i][j] - mx);
      acc[i][j] = p;
      sum += p;
    }
    #pragma unroll
    for (int off = 1; off < 16; off <<= 1) sum += __shfl_xor(sum, off, 16);
    #pragma unroll
    for (int j = 0; j < 4; ++j)
      p_t[(tx * 4 + j) * 68 + ty * 4 + i] = acc[i][j];
    if (tx == 0) {
      const size_t mb = (((size_t)b * NSC + chunk) * NQ + ty * 4 + i) * 2;
      ml[mb] = mx; ml[mb + 1] = sum;
    }
  }
  __syncthreads();

  // ---- step C: o_lat partial = P . c_kv_chunk, c_kv read straight from L1/L2 (no LDS staging, no syncs)
  const size_t obase = ((size_t)b * NSC + chunk) * NQ * RANKC;
  #pragma unroll 1
  for (int rq = 0; rq < 4; ++rq) {
    float acc2[4][8];
    #pragma unroll
    for (int i = 0; i < 4; ++i)
      #pragma unroll
      for (int j = 0; j < 8; ++j) acc2[i][j] = 0.f;
    #pragma unroll 4
    for (int s = 0; s < scnt; ++s) {
      const float4 pv = *reinterpret_cast<const float4*>(&p_t[s * 68 + ty * 4]);
      const float4 c0 = *reinterpret_cast<const float4*>(ckv + (size_t)s * RANKC + rq * 128 + tx * 4);
      const float4 c1 = *reinterpret_cast<const float4*>(ckv + (size_t)s * RANKC + rq * 128 + 64 + tx * 4);
      const float p_[4] = {pv.x, pv.y, pv.z, pv.w};
      const float cv[8] = {c0.x, c0.y, c0.z, c0.w, c1.x, c1.y, c1.z, c1.w};
      #pragma unroll
      for (int i = 0; i < 4; ++i)
        #pragma unroll
        for (int j = 0; j < 8; ++j)
          acc2[i][j] = fmaf(p_[i], cv[j], acc2[i][j]);
    }
    #pragma unroll
    for (int i = 0; i < 4; ++i) {
      const size_t rbase = obase + (size_t)(ty * 4 + i) * RANKC + rq * 128;
      *reinterpret_cast<float4*>(&olat[rbase + tx * 4])      = make_float4(acc2[i][0], acc2[i][1], acc2[i][2], acc2[i][3]);
      *reinterpret_cast<float4*>(&olat[rbase + 64 + tx * 4]) = make_float4(acc2[i][4], acc2[i][5], acc2[i][6], acc2[i][7]);
    }
  }
}

// ---------------- combine partials across chunks -> att[b*64+qi][512]
__global__ __launch_bounds__(256) void k_combine(const float* __restrict__ ml,
                                                 const float* __restrict__ olat,
                                                 float* __restrict__ att) {
  __shared__ float mls[2 * NSC];
  __shared__ float wls[NSC];
  const int bq = blockIdx.x;
  const int b = bq >> 6, qi = bq & 63;
  const int tid = threadIdx.x;
  for (int c = tid; c < 2 * NSC; c += 256)
    mls[c] = ml[(((size_t)b * NSC + (c >> 1)) * NQ + qi) * 2 + (c & 1)];
  __syncthreads();
  float M = -1e30f;
  for (int c = 0; c < NSC; ++c) M = fmaxf(M, mls[2 * c]);
  float L = 0.f;
  for (int c = 0; c < NSC; ++c) L += mls[2 * c + 1] * __expf(mls[2 * c] - M);
  const float invL = 1.0f / L;
  if (tid < NSC) wls[tid] = __expf(mls[2 * tid] - M) * invL;
  __syncthreads();
  float o0 = 0.f, o1 = 0.f;
  for (int c = 0; c < NSC; ++c) {
    const float w = wls[c];
    const size_t base = (((size_t)b * NSC + c) * NQ + qi) * RANKC;
    o0 = fmaf(olat[base + tid], w, o0);
    o1 = fmaf(olat[base + 256 + tid], w, o1);
  }
  att[(size_t)bq * RANKC + tid] = o0;
  att[(size_t)bq * RANKC + 256 + tid] = o1;
}

// ---------------- epilogue: out_head = att . W_up (per head), att staged in LDS
// grid (16 h-colblocks of 128, 8 bt-groups of 4), 256 threads
__global__ __launch_bounds__(256) void k_ohead(const float* __restrict__ att,
                                               const float* __restrict__ wup,
                                               float* __restrict__ ohead) {
  __shared__ float a_s[4][512];
  const int h = blockIdx.x;
  const int btg = blockIdx.y;
  const int tid = threadIdx.x;
  { // stage 4 att rows
    const int rw = tid >> 6;
    const int seg = (tid & 63) * 8;
    const int bt = btg * 4 + rw;
    const int b = bt >> 2, t = bt & 3;
    const float4* s4 = reinterpret_cast<const float4*>(att + ((size_t)b * NQ + h * TT + t) * RANKC + seg);
    float4 v0 = s4[0], v1 = s4[1];
    *reinterpret_cast<float4*>(&a_s[rw][seg])     = v0;
    *reinterpret_cast<float4*>(&a_s[rw][seg + 4]) = v1;
  }
  __syncthreads();
  const int col = h * 128 + (tid & 127);
  const int bth = tid >> 7;
  float acc0 = 0.f, acc1 = 0.f;
  #pragma unroll 8
  for (int r = 0; r < RANKC; ++r) {
    const float wv = wup[(size_t)r * HD + col];
    acc0 = fmaf(a_s[bth * 2 + 0][r], wv, acc0);
    acc1 = fmaf(a_s[bth * 2 + 1][r], wv, acc1);
  }
  const int bt0 = btg * 4 + bth * 2;
  ohead[(size_t)bt0 * HD + col] = acc0;
  ohead[(size_t)(bt0 + 1) * HD + col] = acc1;
}

extern "C" void kernel_launch(void* const* d_in, const int* in_sizes, int n_in,
                              void* d_out, int out_size, void* d_ws, size_t ws_size,
                              hipStream_t stream) {
  const float* x     = (const float*)d_in[0];
  const float* cckv  = (const float*)d_in[1];
  const float* ckr   = (const float*)d_in[2];
  const float* w_q   = (const float*)d_in[3];
  const float* w_qr  = (const float*)d_in[4];
  const float* w_kvd = (const float*)d_in[5];
  const float* w_kvu = (const float*)d_in[6];
  const float* w_kr  = (const float*)d_in[7];
  const float* w_out = (const float*)d_in[8];
  float* out = (float*)d_out;
  float* ws = (float*)d_ws;

  // region A: persistent small buffers
  size_t off = 0;
  float* act   = ws + off; off += 32ull * NACT;                  // 114688
  float* qlat  = ws + off; off += (size_t)BB * NQ * RANKC;       // 262144
  float* qrope = ws + off; off += (size_t)BB * NQ * RRDIM;       // 32768
  float* ckvn  = ws + off; off += (size_t)BB * TT * RANKC;       // 16384
  float* krn   = ws + off; off += (size_t)BB * TT * HH * RRDIM;  // 32768
  float* mlb   = ws + off; off += (size_t)BB * NSC * NQ * 2;     // 66560
  float* att   = ws + off; off += (size_t)BB * NQ * RANKC;       // 262144
  float* ohead = ws + off; off += 32ull * HD;                    // 65536
  // region B: time-shared (part0 -> olat -> part3)
  float* regB  = ws + off;                                        // 17039360 floats max (olat)
  float* part0 = regB;       // 16*32*3584 = 1835008, dead after first k_reduce
  float* olat  = regB;       // 8*65*64*512 = 17039360, dead after k_combine
  float* part3 = regB;       // 16*32*2048 = 1048576

  // phase 0: x projections (K-split 16)
  k_proj<<<dim3(8, 16), 256, 0, stream>>>(x, w_q,   part0, 1024, NACT, 0);
  k_proj<<<dim3(8, 16), 256, 0, stream>>>(x, w_qr,  part0, 1024, NACT, 1024);
  k_proj<<<dim3(4, 16), 256, 0, stream>>>(x, w_kvd, part0, 512,  NACT, 2048);
  k_proj<<<dim3(8, 16), 256, 0, stream>>>(x, w_kr,  part0, 1024, NACT, 2560);
  k_reduce<<<dim3(448), 256, 0, stream>>>(part0, act, 32 * NACT, 16);
  k_qlat<<<dim3(16, 4), 256, 0, stream>>>(act, w_kvu, qlat);
  k_rope<<<dim3(192), 256, 0, stream>>>(act, qrope, ckvn, krn);

  // phase 1: latent attention partials
  k_attn<<<dim3(NSC, BB), 256, 0, stream>>>(cckv, ckr, ckvn, krn, qlat, qrope, mlb, olat);

  // phase 2: combine + epilogues
  k_combine<<<dim3(BB * NQ), 256, 0, stream>>>(mlb, olat, att);
  k_ohead<<<dim3(16, 8), 256, 0, stream>>>(att, w_kvu, ohead);
  k_proj<<<dim3(16, 16), 256, 0, stream>>>(ohead, w_out, part3, 2048, 2048, 0);
  k_reduce<<<dim3(256), 256, 0, stream>>>(part3, out, 32 * HD, 16);
}

// Round 3
// 230.627 us; speedup vs baseline: 3.0026x; 1.7853x over previous
//
#include <hip/hip_runtime.h>
#include <cmath>

#define BB 8
#define TT 4
#define HH 16
#define DDIM 128
#define RRDIM 64
#define CCDIM 64
#define RANKC 512
#define DMODEL 2048
#define S0C 4096
#define NQ 64      // H*T queries per batch
#define HD 2048    // H*D
#define NACT 3584  // 1024 (q) + 1024 (q_rope) + 512 (kv_down) + 1024 (k_rope)
#define NSC 65     // 64 cache chunks of 64 + 1 new-token chunk
#define SCC 64
#define SCALE_ATT 0.08838834764831845f  // 1/sqrt(128)

// padded LDS index for k_proj A-tile
#define AIDX(row, kk) ((row)*132 + (((row)>>2)<<2) + (kk))

// ---------------- fused front projections: part[ks][32][3584] = x[32][2048] x {w_q|w_qr|w_kvd|w_kr}
// grid (28 col-blocks, 16 k-splits), 256 threads
__global__ __launch_bounds__(256) void k_proj4(const float* __restrict__ A,
                                               const float* __restrict__ w0,
                                               const float* __restrict__ w1,
                                               const float* __restrict__ w2,
                                               const float* __restrict__ w3,
                                               float* __restrict__ part) {
  __shared__ float a_lds[4352];
  const int tid = threadIdx.x;
  const int cb = blockIdx.x;
  const int k0 = blockIdx.y * 128;
  const float* W; int N, lc0, off;
  if (cb < 8)       { W = w0; N = 1024; lc0 = cb * 128;        off = 0; }
  else if (cb < 16) { W = w1; N = 1024; lc0 = (cb - 8) * 128;  off = 1024; }
  else if (cb < 20) { W = w2; N = 512;  lc0 = (cb - 16) * 128; off = 2048; }
  else              { W = w3; N = 1024; lc0 = (cb - 20) * 128; off = 2560; }
  {
    const int row = tid >> 3;
    const int kseg = (tid & 7) * 16;
    const float4* s4 = reinterpret_cast<const float4*>(A + (size_t)row * DMODEL + k0 + kseg);
    float4 v0 = s4[0], v1 = s4[1], v2 = s4[2], v3 = s4[3];
    *reinterpret_cast<float4*>(&a_lds[AIDX(row, kseg)])      = v0;
    *reinterpret_cast<float4*>(&a_lds[AIDX(row, kseg + 4)])  = v1;
    *reinterpret_cast<float4*>(&a_lds[AIDX(row, kseg + 8)])  = v2;
    *reinterpret_cast<float4*>(&a_lds[AIDX(row, kseg + 12)]) = v3;
  }
  __syncthreads();
  const int cg = tid & 31;
  const int rg = tid >> 5;
  float acc[4][4];
  #pragma unroll
  for (int r = 0; r < 4; ++r)
    #pragma unroll
    for (int c = 0; c < 4; ++c) acc[r][c] = 0.f;
  #pragma unroll 4
  for (int kk = 0; kk < 128; ++kk) {
    const float4 w4 = *reinterpret_cast<const float4*>(W + (size_t)(k0 + kk) * N + lc0 + cg * 4);
    const float wv[4] = {w4.x, w4.y, w4.z, w4.w};
    #pragma unroll
    for (int r = 0; r < 4; ++r) {
      const float av = a_lds[AIDX(rg * 4 + r, kk)];
      #pragma unroll
      for (int c = 0; c < 4; ++c) acc[r][c] = fmaf(av, wv[c], acc[r][c]);
    }
  }
  #pragma unroll
  for (int r = 0; r < 4; ++r) {
    float4 o = make_float4(acc[r][0], acc[r][1], acc[r][2], acc[r][3]);
    *reinterpret_cast<float4*>(part + ((size_t)blockIdx.y * 32 + rg * 4 + r) * NACT + off + lc0 + cg * 4) = o;
  }
}

// ---------------- plain skinny GEMM for the w_out epilogue
__global__ __launch_bounds__(256) void k_proj(const float* __restrict__ A,
                                              const float* __restrict__ W,
                                              float* __restrict__ part,
                                              int N, int NTOT, int coloff) {
  __shared__ float a_lds[4352];
  const int tid = threadIdx.x;
  const int c0 = blockIdx.x * 128;
  const int k0 = blockIdx.y * 128;
  {
    const int row = tid >> 3;
    const int kseg = (tid & 7) * 16;
    const float4* s4 = reinterpret_cast<const float4*>(A + (size_t)row * DMODEL + k0 + kseg);
    float4 v0 = s4[0], v1 = s4[1], v2 = s4[2], v3 = s4[3];
    *reinterpret_cast<float4*>(&a_lds[AIDX(row, kseg)])      = v0;
    *reinterpret_cast<float4*>(&a_lds[AIDX(row, kseg + 4)])  = v1;
    *reinterpret_cast<float4*>(&a_lds[AIDX(row, kseg + 8)])  = v2;
    *reinterpret_cast<float4*>(&a_lds[AIDX(row, kseg + 12)]) = v3;
  }
  __syncthreads();
  const int cg = tid & 31;
  const int rg = tid >> 5;
  float acc[4][4];
  #pragma unroll
  for (int r = 0; r < 4; ++r)
    #pragma unroll
    for (int c = 0; c < 4; ++c) acc[r][c] = 0.f;
  #pragma unroll 4
  for (int kk = 0; kk < 128; ++kk) {
    const float4 w4 = *reinterpret_cast<const float4*>(W + (size_t)(k0 + kk) * N + c0 + cg * 4);
    const float wv[4] = {w4.x, w4.y, w4.z, w4.w};
    #pragma unroll
    for (int r = 0; r < 4; ++r) {
      const float av = a_lds[AIDX(rg * 4 + r, kk)];
      #pragma unroll
      for (int c = 0; c < 4; ++c) acc[r][c] = fmaf(av, wv[c], acc[r][c]);
    }
  }
  #pragma unroll
  for (int r = 0; r < 4; ++r) {
    float4 o = make_float4(acc[r][0], acc[r][1], acc[r][2], acc[r][3]);
    *reinterpret_cast<float4*>(part + ((size_t)blockIdx.y * 32 + rg * 4 + r) * NTOT + coloff + c0 + cg * 4) = o;
  }
}

// ---------------- reduce K-splits
__global__ __launch_bounds__(256) void k_reduce(const float* __restrict__ part,
                                                float* __restrict__ out, int total, int nsplit) {
  int g = blockIdx.x * 256 + threadIdx.x;
  if (g >= total) return;
  float s = 0.f;
  #pragma unroll 4
  for (int c = 0; c < nsplit; ++c) s += part[(size_t)c * total + g];
  out[g] = s;
}

// ---------------- fused q_lat (W_up absorption) + RoPE + c_kv_new copy
// grid 256: bx<64 -> qlat (h=bx&15, rblk=bx>>4); else rope/copy range
__global__ __launch_bounds__(256) void k_qlatrope(const float* __restrict__ act,
                                                  const float* __restrict__ wup,
                                                  float* __restrict__ qlat,
                                                  float* __restrict__ qrope,
                                                  float* __restrict__ ckvn,
                                                  float* __restrict__ krn) {
  __shared__ float wt[64 * 132];
  __shared__ float a_s[32 * 68];
  const int tid = threadIdx.x;
  const int bx = blockIdx.x;
  if (bx < 64) {
    const int h = bx & 15;
    const int r0 = (bx >> 4) * 128;
    {
      const int r = tid >> 1;
      const int cseg = (tid & 1) * 32;
      const float* src = wup + (size_t)(r0 + r) * HD + h * DDIM + cseg;
      #pragma unroll
      for (int u = 0; u < 8; ++u) {
        const float4 v = *reinterpret_cast<const float4*>(src + u * 4);
        wt[(cseg + u * 4 + 0) * 132 + r] = v.x;
        wt[(cseg + u * 4 + 1) * 132 + r] = v.y;
        wt[(cseg + u * 4 + 2) * 132 + r] = v.z;
        wt[(cseg + u * 4 + 3) * 132 + r] = v.w;
      }
    }
    {
      const int bt = tid >> 3;
      const int cseg = (tid & 7) * 8;
      const float4* s4 = reinterpret_cast<const float4*>(act + (size_t)bt * NACT + h * CCDIM + cseg);
      float4 v0 = s4[0], v1 = s4[1];
      *reinterpret_cast<float4*>(&a_s[bt * 68 + cseg])     = v0;
      *reinterpret_cast<float4*>(&a_s[bt * 68 + cseg + 4]) = v1;
    }
    __syncthreads();
    const int r = tid & 127;
    const int bth = tid >> 7;
    float acc[16];
    #pragma unroll
    for (int i = 0; i < 16; ++i) acc[i] = 0.f;
    #pragma unroll 8
    for (int c = 0; c < 64; ++c) {
      const float wv = wt[c * 132 + r];
      #pragma unroll
      for (int i = 0; i < 16; ++i)
        acc[i] = fmaf(a_s[(bth * 16 + i) * 68 + c], wv, acc[i]);
    }
    #pragma unroll
    for (int i = 0; i < 16; ++i) {
      const int bt = bth * 16 + i;
      const int b = bt >> 2, t = bt & 3;
      qlat[((size_t)(b * NQ) + h * TT + t) * RANKC + r0 + r] = acc[i];
    }
    return;
  }
  int g = (bx - 64) * 256 + tid;
  if (g < BB * TT * HH * 32) {                  // q_rope pairs
    const int hj = g & 31;
    const int h = (g >> 5) & 15;
    const int t = (g >> 9) & 3;
    const int b = g >> 11;
    const float* arow = act + (size_t)(b * TT + t) * NACT + 1024 + h * RRDIM;
    const float x1 = arow[hj], x2 = arow[hj + 32];
    const double fr = (double)(S0C + t) * pow(10000.0, -(double)hj / 32.0);
    const float cs = (float)cos(fr), sn = (float)sin(fr);
    const int qi = h * TT + t;
    qrope[((size_t)b * NQ + qi) * RRDIM + hj]      = x1 * cs - x2 * sn;
    qrope[((size_t)b * NQ + qi) * RRDIM + hj + 32] = x1 * sn + x2 * cs;
    return;
  }
  g -= BB * TT * HH * 32;
  if (g < BB * TT * HH * 32) {                  // k_rope_new pairs -> [b][t][h][R]
    const int hj = g & 31;
    const int h = (g >> 5) & 15;
    const int t = (g >> 9) & 3;
    const int b = g >> 11;
    const float* arow = act + (size_t)(b * TT + t) * NACT + 2560 + h * RRDIM;
    const float x1 = arow[hj], x2 = arow[hj + 32];
    const double fr = (double)(S0C + t) * pow(10000.0, -(double)hj / 32.0);
    const float cs = (float)cos(fr), sn = (float)sin(fr);
    krn[((size_t)(b * TT + t) * HH + h) * RRDIM + hj]      = x1 * cs - x2 * sn;
    krn[((size_t)(b * TT + t) * HH + h) * RRDIM + hj + 32] = x1 * sn + x2 * cs;
    return;
  }
  g -= BB * TT * HH * 32;
  if (g < BB * TT * RANKC) {                    // c_kv_new copy
    ckvn[g] = act[(size_t)(g >> 9) * NACT + 2048 + (g & 511)];
  }
}

// ---------------- phase 1: latent flash attention partials per (b, chunk)
// grid (8 b, 65 chunks) -> XCD = b (round-robin on linear id mod 8). 256 thr = 16 ty(head) x 16 tx.
__global__ __launch_bounds__(256) void k_attn(
    const float* __restrict__ cache_ckv, const float* __restrict__ cache_kr,
    const float* __restrict__ ckvn, const float* __restrict__ krn,
    const float* __restrict__ qlat, const float* __restrict__ qrope,
    float* __restrict__ ml, float* __restrict__ olat) {
  __shared__ float sm[13056];      // [0,8704): stage dbuf region; [8704,13056): p_t / rs_lds
  float* const A0  = sm;           // 32*68
  float* const Bt0 = sm + 2176;
  float* const A1  = sm + 4352;
  float* const Bt1 = sm + 6528;
  float* const p_t = sm + 8704;    // 64*68, also rs_lds in rope phase
  float* const qr_l = sm;          // rope phase only (64*68 = 4352 fits region)
  float* const CS0 = sm;           // step C dbuf (32*136 = 4352 each)
  float* const CS1 = sm + 4352;

  const int tid = threadIdx.x;
  const int ty = tid >> 4, tx = tid & 15;
  const int b = blockIdx.x, chunk = blockIdx.y;
  int scnt;
  const float *ckv, *kr;
  if (chunk < 64) {
    scnt = SCC;
    ckv = cache_ckv + ((size_t)b * S0C + (size_t)chunk * SCC) * RANKC;
    kr  = cache_kr  + ((size_t)b * S0C + (size_t)chunk * SCC) * (HH * RRDIM);
  } else {
    scnt = TT;
    ckv = ckvn + (size_t)b * TT * RANKC;
    kr  = krn  + (size_t)b * TT * (HH * RRDIM);
  }
  const float* qlb = qlat + (size_t)b * NQ * RANKC;
  const float* qrb = qrope + (size_t)b * NQ * RRDIM;

  // ---- rope phase: coalesced k_rope reads, shfl-reduced dots -> rs (in p_t region)
  {
    const int row = tid >> 2;
    const int seg = (tid & 3) * 16;
    const float4* s4 = reinterpret_cast<const float4*>(qrb + (size_t)row * RRDIM + seg);
    float4 v0 = s4[0], v1 = s4[1], v2 = s4[2], v3 = s4[3];
    float4* d4 = reinterpret_cast<float4*>(&qr_l[row * 68 + seg]);
    d4[0] = v0; d4[1] = v1; d4[2] = v2; d4[3] = v3;
  }
  __syncthreads();
  {
    const int l = tx;      // lane within 16-group, ty = head
    for (int it = 0; it < scnt; ++it) {
      const float4 kv = *reinterpret_cast<const float4*>(kr + (size_t)(it * HH + ty) * RRDIM + l * 4);
      float p0, p1, p2, p3;
      {
        const float4 q0 = *reinterpret_cast<const float4*>(&qr_l[(ty * 4 + 0) * 68 + l * 4]);
        const float4 q1 = *reinterpret_cast<const float4*>(&qr_l[(ty * 4 + 1) * 68 + l * 4]);
        const float4 q2 = *reinterpret_cast<const float4*>(&qr_l[(ty * 4 + 2) * 68 + l * 4]);
        const float4 q3 = *reinterpret_cast<const float4*>(&qr_l[(ty * 4 + 3) * 68 + l * 4]);
        p0 = kv.x*q0.x + kv.y*q0.y + kv.z*q0.z + kv.w*q0.w;
        p1 = kv.x*q1.x + kv.y*q1.y + kv.z*q1.z + kv.w*q1.w;
        p2 = kv.x*q2.x + kv.y*q2.y + kv.z*q2.z + kv.w*q2.w;
        p3 = kv.x*q3.x + kv.y*q3.y + kv.z*q3.z + kv.w*q3.w;
      }
      #pragma unroll
      for (int off = 1; off < 16; off <<= 1) {
        p0 += __shfl_xor(p0, off, 16);
        p1 += __shfl_xor(p1, off, 16);
        p2 += __shfl_xor(p2, off, 16);
        p3 += __shfl_xor(p3, off, 16);
      }
      if (l < 4) {
        const float v = (l == 0) ? p0 : (l == 1) ? p1 : (l == 2) ? p2 : p3;
        p_t[it * 68 + ty * 4 + l] = v;   // rs_lds[s][qi]
      }
    }
  }
  __syncthreads();

  // acc initialized from rope scores (garbage for s>=scnt is masked at softmax)
  float acc[4][4];
  #pragma unroll
  for (int i = 0; i < 4; ++i)
    #pragma unroll
    for (int j = 0; j < 4; ++j)
      acc[i][j] = p_t[(tx * 4 + j) * 68 + ty * 4 + i];

  // ---- step A: content scores += q_lat . c_kv (K=512, double-buffered 32-wide slices)
  auto stageAB = [&](int kc, float* aDst, float* bDst) {
    const int row = tid >> 2;
    const int kb = (tid & 3) * 8;
    {
      const float4* s4 = reinterpret_cast<const float4*>(qlb + (size_t)row * RANKC + kc + kb);
      float4 v0 = s4[0], v1 = s4[1];
      aDst[(kb+0)*68+row]=v0.x; aDst[(kb+1)*68+row]=v0.y; aDst[(kb+2)*68+row]=v0.z; aDst[(kb+3)*68+row]=v0.w;
      aDst[(kb+4)*68+row]=v1.x; aDst[(kb+5)*68+row]=v1.y; aDst[(kb+6)*68+row]=v1.z; aDst[(kb+7)*68+row]=v1.w;
    }
    {
      float4 v0, v1;
      if (row < scnt) {
        const float4* s4 = reinterpret_cast<const float4*>(ckv + (size_t)row * RANKC + kc + kb);
        v0 = s4[0]; v1 = s4[1];
      } else { v0 = make_float4(0.f,0.f,0.f,0.f); v1 = v0; }
      bDst[(kb+0)*68+row]=v0.x; bDst[(kb+1)*68+row]=v0.y; bDst[(kb+2)*68+row]=v0.z; bDst[(kb+3)*68+row]=v0.w;
      bDst[(kb+4)*68+row]=v1.x; bDst[(kb+5)*68+row]=v1.y; bDst[(kb+6)*68+row]=v1.z; bDst[(kb+7)*68+row]=v1.w;
    }
  };
  stageAB(0, A0, Bt0);
  __syncthreads();
  for (int kt = 0; kt < 16; ++kt) {
    const float* aCur = (kt & 1) ? A1 : A0;
    const float* bCur = (kt & 1) ? Bt1 : Bt0;
    if (kt < 15) stageAB((kt + 1) * 32, (kt & 1) ? A0 : A1, (kt & 1) ? Bt0 : Bt1);
    #pragma unroll 8
    for (int kk = 0; kk < 32; ++kk) {
      const float4 av = *reinterpret_cast<const float4*>(&aCur[kk * 68 + ty * 4]);
      const float4 bv = *reinterpret_cast<const float4*>(&bCur[kk * 68 + tx * 4]);
      const float a_[4] = {av.x, av.y, av.z, av.w};
      const float b_[4] = {bv.x, bv.y, bv.z, bv.w};
      #pragma unroll
      for (int i = 0; i < 4; ++i)
        #pragma unroll
        for (int j = 0; j < 4; ++j)
          acc[i][j] = fmaf(a_[i], b_[j], acc[i][j]);
    }
    __syncthreads();
  }

  // ---- partial softmax per q-row (row spread over 16 tx lanes)
  #pragma unroll
  for (int i = 0; i < 4; ++i) {
    float mx = -1e30f;
    #pragma unroll
    for (int j = 0; j < 4; ++j) {
      const int s = tx * 4 + j;
      float v = (s < scnt) ? acc[i][j] * SCALE_ATT : -1e30f;
      acc[i][j] = v;
      mx = fmaxf(mx, v);
    }
    #pragma unroll
    for (int off = 1; off < 16; off <<= 1) mx = fmaxf(mx, __shfl_xor(mx, off, 16));
    float sum = 0.f;
    #pragma unroll
    for (int j = 0; j < 4; ++j) {
      const float p = __expf(acc[i][j] - mx);
      acc[i][j] = p;
      sum += p;
    }
    #pragma unroll
    for (int off = 1; off < 16; off <<= 1) sum += __shfl_xor(sum, off, 16);
    #pragma unroll
    for (int j = 0; j < 4; ++j)
      p_t[(tx * 4 + j) * 68 + ty * 4 + i] = acc[i][j];
    if (tx == 0) {
      const size_t mb = (((size_t)b * NSC + chunk) * NQ + ty * 4 + i) * 2;
      ml[mb] = mx; ml[mb + 1] = sum;
    }
  }

  // ---- step C: o_lat partial = P . c_kv, LDS-staged (32s x 128r tiles, double-buffered)
  auto stageCS = [&](int step, float* dst) {
    const int rq = step >> 1, sck = step & 1;
    const int s_loc = tid >> 3;
    const int c16 = (tid & 7) * 16;
    const int s = sck * 32 + s_loc;
    float4 v[4];
    if (s < scnt) {
      const float4* s4 = reinterpret_cast<const float4*>(ckv + (size_t)s * RANKC + rq * 128 + c16);
      v[0]=s4[0]; v[1]=s4[1]; v[2]=s4[2]; v[3]=s4[3];
    } else { v[0]=make_float4(0.f,0.f,0.f,0.f); v[1]=v[0]; v[2]=v[0]; v[3]=v[0]; }
    float4* d4 = reinterpret_cast<float4*>(&dst[s_loc * 136 + c16]);
    d4[0]=v[0]; d4[1]=v[1]; d4[2]=v[2]; d4[3]=v[3];
  };
  stageCS(0, CS0);
  __syncthreads();   // also covers p_t writes above
  const size_t obase = ((size_t)b * NSC + chunk) * NQ * RANKC;
  float acc2[4][8];
  for (int step = 0; step < 8; ++step) {
    const float* cs = (step & 1) ? CS1 : CS0;
    if (step < 7) stageCS(step + 1, (step & 1) ? CS0 : CS1);
    const int rq = step >> 1, sck = step & 1;
    if (sck == 0) {
      #pragma unroll
      for (int i = 0; i < 4; ++i)
        #pragma unroll
        for (int j = 0; j < 8; ++j) acc2[i][j] = 0.f;
    }
    #pragma unroll 8
    for (int ss = 0; ss < 32; ++ss) {
      const int s = sck * 32 + ss;
      const float4 pv = *reinterpret_cast<const float4*>(&p_t[s * 68 + ty * 4]);
      const float4 c0 = *reinterpret_cast<const float4*>(&cs[ss * 136 + tx * 4]);
      const float4 c1 = *reinterpret_cast<const float4*>(&cs[ss * 136 + 64 + tx * 4]);
      const float p_[4] = {pv.x, pv.y, pv.z, pv.w};
      const float cv[8] = {c0.x, c0.y, c0.z, c0.w, c1.x, c1.y, c1.z, c1.w};
      #pragma unroll
      for (int i = 0; i < 4; ++i)
        #pragma unroll
        for (int j = 0; j < 8; ++j)
          acc2[i][j] = fmaf(p_[i], cv[j], acc2[i][j]);
    }
    if (sck == 1) {
      #pragma unroll
      for (int i = 0; i < 4; ++i) {
        const size_t rbase = obase + (size_t)(ty * 4 + i) * RANKC + rq * 128;
        *reinterpret_cast<float4*>(&olat[rbase + tx * 4])      = make_float4(acc2[i][0], acc2[i][1], acc2[i][2], acc2[i][3]);
        *reinterpret_cast<float4*>(&olat[rbase + 64 + tx * 4]) = make_float4(acc2[i][4], acc2[i][5], acc2[i][6], acc2[i][7]);
      }
    }
    __syncthreads();
  }
}

// ---------------- fused combine + out_head epilogue
// grid (16 h, 8 b), 512 threads
__global__ __launch_bounds__(512) void k_combF(const float* __restrict__ ml,
                                               const float* __restrict__ olat,
                                               const float* __restrict__ wup,
                                               float* __restrict__ ohead) {
  __shared__ float wrow[4][66];
  __shared__ float att_lds[4][516];
  const int h = blockIdx.x, b = blockIdx.y;
  const int tid = threadIdx.x;
  const int wave = tid >> 6;
  const int i = wave >> 1;          // q-row within head: t = i
  const int rhalf = wave & 1;
  const int rl = tid & 63;
  const int qi = h * TT + i;
  // stats (duplicated across the rhalf pair)
  float m1 = -1e30f, l1 = 0.f, m2 = -1e30f, l2 = 0.f;
  {
    const size_t base = (((size_t)b * NSC + rl) * NQ + qi) * 2;
    m1 = ml[base]; l1 = ml[base + 1];
    if (rl == 0) {
      const size_t b2 = (((size_t)b * NSC + 64) * NQ + qi) * 2;
      m2 = ml[b2]; l2 = ml[b2 + 1];
    }
  }
  float M = fmaxf(m1, m2);
  #pragma unroll
  for (int off = 1; off < 64; off <<= 1) M = fmaxf(M, __shfl_xor(M, off));
  float L = l1 * __expf(m1 - M) + ((rl == 0) ? l2 * __expf(m2 - M) : 0.f);
  #pragma unroll
  for (int off = 1; off < 64; off <<= 1) L += __shfl_xor(L, off);
  const float invL = 1.0f / L;
  wrow[i][rl] = __expf(m1 - M) * invL;
  if (rl == 0) wrow[i][64] = __expf(m2 - M) * invL;
  __syncthreads();
  // o accumulation: wave covers r-half [rhalf*256, +256)
  const int r0 = rhalf * 256 + rl * 4;
  float o0 = 0.f, o1 = 0.f, o2 = 0.f, o3 = 0.f;
  for (int c = 0; c < NSC; ++c) {
    const float w = wrow[i][c];
    const float4 v = *reinterpret_cast<const float4*>(olat + (((size_t)b * NSC + c) * NQ + qi) * RANKC + r0);
    o0 = fmaf(v.x, w, o0); o1 = fmaf(v.y, w, o1); o2 = fmaf(v.z, w, o2); o3 = fmaf(v.w, w, o3);
  }
  *reinterpret_cast<float4*>(&att_lds[i][r0]) = make_float4(o0, o1, o2, o3);
  __syncthreads();
  // out_head for cols h*128..+128, rows (b, t=0..3)
  const int col = tid & 127;
  const int t = tid >> 7;
  float acc = 0.f;
  #pragma unroll 8
  for (int r = 0; r < RANKC; ++r)
    acc = fmaf(att_lds[t][r], wup[(size_t)r * HD + h * DDIM + col], acc);
  ohead[(size_t)(b * TT + t) * HD + h * DDIM + col] = acc;
}

extern "C" void kernel_launch(void* const* d_in, const int* in_sizes, int n_in,
                              void* d_out, int out_size, void* d_ws, size_t ws_size,
                              hipStream_t stream) {
  const float* x     = (const float*)d_in[0];
  const float* cckv  = (const float*)d_in[1];
  const float* ckr   = (const float*)d_in[2];
  const float* w_q   = (const float*)d_in[3];
  const float* w_qr  = (const float*)d_in[4];
  const float* w_kvd = (const float*)d_in[5];
  const float* w_kvu = (const float*)d_in[6];
  const float* w_kr  = (const float*)d_in[7];
  const float* w_out = (const float*)d_in[8];
  float* out = (float*)d_out;
  float* ws = (float*)d_ws;

  size_t off = 0;
  float* act   = ws + off; off += 32ull * NACT;                  // 114688
  float* qlat  = ws + off; off += (size_t)BB * NQ * RANKC;       // 262144
  float* qrope = ws + off; off += (size_t)BB * NQ * RRDIM;       // 32768
  float* ckvn  = ws + off; off += (size_t)BB * TT * RANKC;       // 16384
  float* krn   = ws + off; off += (size_t)BB * TT * HH * RRDIM;  // 32768
  float* mlb   = ws + off; off += (size_t)BB * NSC * NQ * 2;     // 66560
  float* ohead = ws + off; off += 32ull * HD;                    // 65536
  // region B (time-shared): part0 -> olat -> part3
  float* regB  = ws + off;
  float* part0 = regB;        // 16*32*3584
  float* olat  = regB;        // 8*65*64*512 = 17039360 (max)
  float* part3 = regB;        // 16*32*2048

  k_proj4<<<dim3(28, 16), 256, 0, stream>>>(x, w_q, w_qr, w_kvd, w_kr, part0);
  k_reduce<<<dim3(448), 256, 0, stream>>>(part0, act, 32 * NACT, 16);
  k_qlatrope<<<dim3(256), 256, 0, stream>>>(act, w_kvu, qlat, qrope, ckvn, krn);

  k_attn<<<dim3(BB, NSC), 256, 0, stream>>>(cckv, ckr, ckvn, krn, qlat, qrope, mlb, olat);

  k_combF<<<dim3(16, 8), 512, 0, stream>>>(mlb, olat, w_kvu, ohead);
  k_proj<<<dim3(16, 16), 256, 0, stream>>>(ohead, w_out, part3, 2048, 2048, 0);
  k_reduce<<<dim3(256), 256, 0, stream>>>(part3, out, 32 * HD, 16);
}

// Round 4
// 221.078 us; speedup vs baseline: 3.1323x; 1.0432x over previous
//
#include <hip/hip_runtime.h>
#include <cmath>

#define BB 8
#define TT 4
#define HH 16
#define DDIM 128
#define RRDIM 64
#define CCDIM 64
#define RANKC 512
#define DMODEL 2048
#define S0C 4096
#define NQ 64      // H*T queries per batch
#define HD 2048    // H*D
#define NACT 3584  // 1024 (q) + 1024 (q_rope) + 512 (kv_down) + 1024 (k_rope)
#define NSC 65     // 64 cache chunks of 64 + 1 new-token chunk
#define SPAD 4160  // padded S for rope-score rows
#define SCALE_ATT 0.08838834764831845f  // 1/sqrt(128)

// padded LDS index for k_proj A-tile
#define AIDX(row, kk) ((row)*132 + (((row)>>2)<<2) + (kk))

static __device__ __forceinline__ unsigned short f2bf(float x) {
  unsigned u = __float_as_uint(x);
  u += 0x7FFFu + ((u >> 16) & 1u);
  return (unsigned short)(u >> 16);
}
static __device__ __forceinline__ float bf2f(unsigned v16) {
  return __uint_as_float(v16 << 16);
}
static __device__ __forceinline__ unsigned pk2(float a, float b) {
  return (unsigned)f2bf(a) | ((unsigned)f2bf(b) << 16);
}

// ---------------- fused front projections: part[ks][32][3584] = x[32][2048] x {w_q|w_qr|w_kvd|w_kr}
__global__ __launch_bounds__(256) void k_proj4(const float* __restrict__ A,
                                               const float* __restrict__ w0,
                                               const float* __restrict__ w1,
                                               const float* __restrict__ w2,
                                               const float* __restrict__ w3,
                                               float* __restrict__ part) {
  __shared__ float a_lds[4352];
  const int tid = threadIdx.x;
  const int cb = blockIdx.x;
  const int k0 = blockIdx.y * 128;
  const float* W; int N, lc0, off;
  if (cb < 8)       { W = w0; N = 1024; lc0 = cb * 128;        off = 0; }
  else if (cb < 16) { W = w1; N = 1024; lc0 = (cb - 8) * 128;  off = 1024; }
  else if (cb < 20) { W = w2; N = 512;  lc0 = (cb - 16) * 128; off = 2048; }
  else              { W = w3; N = 1024; lc0 = (cb - 20) * 128; off = 2560; }
  {
    const int row = tid >> 3;
    const int kseg = (tid & 7) * 16;
    const float4* s4 = reinterpret_cast<const float4*>(A + (size_t)row * DMODEL + k0 + kseg);
    float4 v0 = s4[0], v1 = s4[1], v2 = s4[2], v3 = s4[3];
    *reinterpret_cast<float4*>(&a_lds[AIDX(row, kseg)])      = v0;
    *reinterpret_cast<float4*>(&a_lds[AIDX(row, kseg + 4)])  = v1;
    *reinterpret_cast<float4*>(&a_lds[AIDX(row, kseg + 8)])  = v2;
    *reinterpret_cast<float4*>(&a_lds[AIDX(row, kseg + 12)]) = v3;
  }
  __syncthreads();
  const int cg = tid & 31;
  const int rg = tid >> 5;
  float acc[4][4];
  #pragma unroll
  for (int r = 0; r < 4; ++r)
    #pragma unroll
    for (int c = 0; c < 4; ++c) acc[r][c] = 0.f;
  #pragma unroll 4
  for (int kk = 0; kk < 128; ++kk) {
    const float4 w4 = *reinterpret_cast<const float4*>(W + (size_t)(k0 + kk) * N + lc0 + cg * 4);
    const float wv[4] = {w4.x, w4.y, w4.z, w4.w};
    #pragma unroll
    for (int r = 0; r < 4; ++r) {
      const float av = a_lds[AIDX(rg * 4 + r, kk)];
      #pragma unroll
      for (int c = 0; c < 4; ++c) acc[r][c] = fmaf(av, wv[c], acc[r][c]);
    }
  }
  #pragma unroll
  for (int r = 0; r < 4; ++r) {
    float4 o = make_float4(acc[r][0], acc[r][1], acc[r][2], acc[r][3]);
    *reinterpret_cast<float4*>(part + ((size_t)blockIdx.y * 32 + rg * 4 + r) * NACT + off + lc0 + cg * 4) = o;
  }
}

// ---------------- plain skinny GEMM for the w_out epilogue
__global__ __launch_bounds__(256) void k_proj(const float* __restrict__ A,
                                              const float* __restrict__ W,
                                              float* __restrict__ part,
                                              int N, int NTOT, int coloff) {
  __shared__ float a_lds[4352];
  const int tid = threadIdx.x;
  const int c0 = blockIdx.x * 128;
  const int k0 = blockIdx.y * 128;
  {
    const int row = tid >> 3;
    const int kseg = (tid & 7) * 16;
    const float4* s4 = reinterpret_cast<const float4*>(A + (size_t)row * DMODEL + k0 + kseg);
    float4 v0 = s4[0], v1 = s4[1], v2 = s4[2], v3 = s4[3];
    *reinterpret_cast<float4*>(&a_lds[AIDX(row, kseg)])      = v0;
    *reinterpret_cast<float4*>(&a_lds[AIDX(row, kseg + 4)])  = v1;
    *reinterpret_cast<float4*>(&a_lds[AIDX(row, kseg + 8)])  = v2;
    *reinterpret_cast<float4*>(&a_lds[AIDX(row, kseg + 12)]) = v3;
  }
  __syncthreads();
  const int cg = tid & 31;
  const int rg = tid >> 5;
  float acc[4][4];
  #pragma unroll
  for (int r = 0; r < 4; ++r)
    #pragma unroll
    for (int c = 0; c < 4; ++c) acc[r][c] = 0.f;
  #pragma unroll 4
  for (int kk = 0; kk < 128; ++kk) {
    const float4 w4 = *reinterpret_cast<const float4*>(W + (size_t)(k0 + kk) * N + c0 + cg * 4);
    const float wv[4] = {w4.x, w4.y, w4.z, w4.w};
    #pragma unroll
    for (int r = 0; r < 4; ++r) {
      const float av = a_lds[AIDX(rg * 4 + r, kk)];
      #pragma unroll
      for (int c = 0; c < 4; ++c) acc[r][c] = fmaf(av, wv[c], acc[r][c]);
    }
  }
  #pragma unroll
  for (int r = 0; r < 4; ++r) {
    float4 o = make_float4(acc[r][0], acc[r][1], acc[r][2], acc[r][3]);
    *reinterpret_cast<float4*>(part + ((size_t)blockIdx.y * 32 + rg * 4 + r) * NTOT + coloff + c0 + cg * 4) = o;
  }
}

// ---------------- reduce K-splits
__global__ __launch_bounds__(256) void k_reduce(const float* __restrict__ part,
                                                float* __restrict__ out, int total, int nsplit) {
  int g = blockIdx.x * 256 + threadIdx.x;
  if (g >= total) return;
  float s = 0.f;
  #pragma unroll 4
  for (int c = 0; c < nsplit; ++c) s += part[(size_t)c * total + g];
  out[g] = s;
}

// ---------------- fused q_lat (W_up absorption) + RoPE + c_kv_new copy
__global__ __launch_bounds__(256) void k_qlatrope(const float* __restrict__ act,
                                                  const float* __restrict__ wup,
                                                  float* __restrict__ qlat,
                                                  float* __restrict__ qrope,
                                                  float* __restrict__ ckvn,
                                                  float* __restrict__ krn) {
  __shared__ float wt[64 * 132];
  __shared__ float a_s[32 * 68];
  const int tid = threadIdx.x;
  const int bx = blockIdx.x;
  if (bx < 64) {
    const int h = bx & 15;
    const int r0 = (bx >> 4) * 128;
    {
      const int r = tid >> 1;
      const int cseg = (tid & 1) * 32;
      const float* src = wup + (size_t)(r0 + r) * HD + h * DDIM + cseg;
      #pragma unroll
      for (int u = 0; u < 8; ++u) {
        const float4 v = *reinterpret_cast<const float4*>(src + u * 4);
        wt[(cseg + u * 4 + 0) * 132 + r] = v.x;
        wt[(cseg + u * 4 + 1) * 132 + r] = v.y;
        wt[(cseg + u * 4 + 2) * 132 + r] = v.z;
        wt[(cseg + u * 4 + 3) * 132 + r] = v.w;
      }
    }
    {
      const int bt = tid >> 3;
      const int cseg = (tid & 7) * 8;
      const float4* s4 = reinterpret_cast<const float4*>(act + (size_t)bt * NACT + h * CCDIM + cseg);
      float4 v0 = s4[0], v1 = s4[1];
      *reinterpret_cast<float4*>(&a_s[bt * 68 + cseg])     = v0;
      *reinterpret_cast<float4*>(&a_s[bt * 68 + cseg + 4]) = v1;
    }
    __syncthreads();
    const int r = tid & 127;
    const int bth = tid >> 7;
    float acc[16];
    #pragma unroll
    for (int i = 0; i < 16; ++i) acc[i] = 0.f;
    #pragma unroll 8
    for (int c = 0; c < 64; ++c) {
      const float wv = wt[c * 132 + r];
      #pragma unroll
      for (int i = 0; i < 16; ++i)
        acc[i] = fmaf(a_s[(bth * 16 + i) * 68 + c], wv, acc[i]);
    }
    #pragma unroll
    for (int i = 0; i < 16; ++i) {
      const int bt = bth * 16 + i;
      const int b = bt >> 2, t = bt & 3;
      qlat[((size_t)(b * NQ) + h * TT + t) * RANKC + r0 + r] = acc[i];
    }
    return;
  }
  int g = (bx - 64) * 256 + tid;
  if (g < BB * TT * HH * 32) {                  // q_rope pairs
    const int hj = g & 31;
    const int h = (g >> 5) & 15;
    const int t = (g >> 9) & 3;
    const int b = g >> 11;
    const float* arow = act + (size_t)(b * TT + t) * NACT + 1024 + h * RRDIM;
    const float x1 = arow[hj], x2 = arow[hj + 32];
    const double fr = (double)(S0C + t) * pow(10000.0, -(double)hj / 32.0);
    const float cs = (float)cos(fr), sn = (float)sin(fr);
    const int qi = h * TT + t;
    qrope[((size_t)b * NQ + qi) * RRDIM + hj]      = x1 * cs - x2 * sn;
    qrope[((size_t)b * NQ + qi) * RRDIM + hj + 32] = x1 * sn + x2 * cs;
    return;
  }
  g -= BB * TT * HH * 32;
  if (g < BB * TT * HH * 32) {                  // k_rope_new pairs -> [b][t][h][R]
    const int hj = g & 31;
    const int h = (g >> 5) & 15;
    const int t = (g >> 9) & 3;
    const int b = g >> 11;
    const float* arow = act + (size_t)(b * TT + t) * NACT + 2560 + h * RRDIM;
    const float x1 = arow[hj], x2 = arow[hj + 32];
    const double fr = (double)(S0C + t) * pow(10000.0, -(double)hj / 32.0);
    const float cs = (float)cos(fr), sn = (float)sin(fr);
    krn[((size_t)(b * TT + t) * HH + h) * RRDIM + hj]      = x1 * cs - x2 * sn;
    krn[((size_t)(b * TT + t) * HH + h) * RRDIM + hj + 32] = x1 * sn + x2 * cs;
    return;
  }
  g -= BB * TT * HH * 32;
  if (g < BB * TT * RANKC) {                    // c_kv_new copy
    ckvn[g] = act[(size_t)(g >> 9) * NACT + 2048 + (g & 511)];
  }
}

// ---------------- rope scores: rs[b][h][t][SPAD] = q_rope[b,h,t,:] . k_rope[b,s,h,:]
// grid (128 = b*16+h, 9 s-chunks of 512), 256 threads; quad of lanes per s position
__global__ __launch_bounds__(256) void k_rscore(const float* __restrict__ cache_kr,
                                                const float* __restrict__ krn,
                                                const float* __restrict__ qrope,
                                                float* __restrict__ rs) {
  const int bh = blockIdx.x;
  const int b = bh >> 4, h = bh & 15;
  const int tid = threadIdx.x;
  const int ql = tid & 3;
  // q fragment: q[t][ql*16 .. +16)
  float4 qf[4][4];
  const float* qrb = qrope + ((size_t)b * NQ + h * TT) * RRDIM;
  #pragma unroll
  for (int t = 0; t < 4; ++t)
    #pragma unroll
    for (int u = 0; u < 4; ++u)
      qf[t][u] = *reinterpret_cast<const float4*>(qrb + t * RRDIM + ql * 16 + u * 4);
  const int s0 = blockIdx.y * 512;
  #pragma unroll 1
  for (int pass = 0; pass < 8; ++pass) {
    const int s = s0 + pass * 64 + (tid >> 2);
    if (s < 4100) {
      const float* krow = (s < S0C)
        ? cache_kr + (((size_t)b * S0C + s) * HH + h) * RRDIM
        : krn + (((size_t)b * TT + (s - S0C)) * HH + h) * RRDIM;
      float p[4] = {0.f, 0.f, 0.f, 0.f};
      #pragma unroll
      for (int u = 0; u < 4; ++u) {
        const float4 kv = *reinterpret_cast<const float4*>(krow + ql * 16 + u * 4);
        #pragma unroll
        for (int t = 0; t < 4; ++t) {
          p[t] += kv.x * qf[t][u].x + kv.y * qf[t][u].y
                + kv.z * qf[t][u].z + kv.w * qf[t][u].w;
        }
      }
      #pragma unroll
      for (int t = 0; t < 4; ++t) {
        p[t] += __shfl_xor(p[t], 1, 4);
        p[t] += __shfl_xor(p[t], 2, 4);
      }
      rs[((size_t)bh * 4 + ql) * SPAD + s] = p[ql];
    }
  }
}

// ---------------- phase 1: latent flash attention partials per (b, chunk)
// grid (8 b, 65 chunks); 256 thr = 16 ty(head) x 16 tx; T14 async-stage split throughout
__global__ __launch_bounds__(256) void k_attn(
    const float* __restrict__ cache_ckv, const float* __restrict__ ckvn,
    const float* __restrict__ rs, const float* __restrict__ qlat,
    float* __restrict__ ml, unsigned short* __restrict__ olat) {
  __shared__ float sm[13056];
  float* const A0 = sm;             // 32*68
  float* const A1 = sm + 2176;
  float* const B0 = sm + 4352;
  float* const B1 = sm + 6528;
  float* const p_t = sm + 8704;     // 64*68
  float* const CS0 = sm;            // step C dbuf (32*136 each), reuses A/B region
  float* const CS1 = sm + 4352;

  const int tid = threadIdx.x;
  const int ty = tid >> 4, tx = tid & 15;
  const int b = blockIdx.x, chunk = blockIdx.y;
  const int scnt = (chunk < 64) ? 64 : TT;
  const float* ckv = (chunk < 64)
      ? cache_ckv + ((size_t)b * S0C + (size_t)chunk * 64) * RANKC
      : ckvn + (size_t)b * TT * RANKC;
  const float* qlb = qlat + (size_t)b * NQ * RANKC;

  // ---- init acc from precomputed rope scores (garbage beyond scnt masked at softmax)
  float acc[4][4];
  {
    const int sg = chunk * 64 + tx * 4;
    #pragma unroll
    for (int i = 0; i < 4; ++i) {
      const float4 v = *reinterpret_cast<const float4*>(
          rs + (((size_t)(b * HH + ty)) * 4 + i) * SPAD + sg);
      acc[i][0] = v.x; acc[i][1] = v.y; acc[i][2] = v.z; acc[i][3] = v.w;
    }
  }

  // ---- step A: content scores += q_lat . c_kv (K=512, dbuf + async-stage split)
  const int row = tid >> 2;         // 0..63
  const int kb = (tid & 3) * 8;     // k sub-offset
  float4 ra0, ra1, rb0, rb1;
  auto loadAB = [&](int kc) {
    const float4* a4 = reinterpret_cast<const float4*>(qlb + (size_t)row * RANKC + kc + kb);
    ra0 = a4[0]; ra1 = a4[1];
    if (row < scnt) {
      const float4* b4 = reinterpret_cast<const float4*>(ckv + (size_t)row * RANKC + kc + kb);
      rb0 = b4[0]; rb1 = b4[1];
    } else { rb0 = make_float4(0.f, 0.f, 0.f, 0.f); rb1 = rb0; }
  };
  auto writeAB = [&](float* aD, float* bD) {
    aD[(kb+0)*68+row]=ra0.x; aD[(kb+1)*68+row]=ra0.y; aD[(kb+2)*68+row]=ra0.z; aD[(kb+3)*68+row]=ra0.w;
    aD[(kb+4)*68+row]=ra1.x; aD[(kb+5)*68+row]=ra1.y; aD[(kb+6)*68+row]=ra1.z; aD[(kb+7)*68+row]=ra1.w;
    bD[(kb+0)*68+row]=rb0.x; bD[(kb+1)*68+row]=rb0.y; bD[(kb+2)*68+row]=rb0.z; bD[(kb+3)*68+row]=rb0.w;
    bD[(kb+4)*68+row]=rb1.x; bD[(kb+5)*68+row]=rb1.y; bD[(kb+6)*68+row]=rb1.z; bD[(kb+7)*68+row]=rb1.w;
  };
  loadAB(0);
  writeAB(A0, B0);
  __syncthreads();
  for (int kt = 0; kt < 16; ++kt) {
    if (kt < 15) loadAB((kt + 1) * 32);          // issue early (T14)
    const float* aC = (kt & 1) ? A1 : A0;
    const float* bC = (kt & 1) ? B1 : B0;
    #pragma unroll 8
    for (int kk = 0; kk < 32; ++kk) {
      const float4 av = *reinterpret_cast<const float4*>(&aC[kk * 68 + ty * 4]);
      const float4 bv = *reinterpret_cast<const float4*>(&bC[kk * 68 + tx * 4]);
      const float a_[4] = {av.x, av.y, av.z, av.w};
      const float b_[4] = {bv.x, bv.y, bv.z, bv.w};
      #pragma unroll
      for (int i = 0; i < 4; ++i)
        #pragma unroll
        for (int j = 0; j < 4; ++j)
          acc[i][j] = fmaf(a_[i], b_[j], acc[i][j]);
    }
    if (kt < 15) writeAB((kt & 1) ? A0 : A1, (kt & 1) ? B0 : B1);  // write late
    __syncthreads();
  }

  // ---- partial softmax per q-row (row spread over 16 tx lanes)
  #pragma unroll
  for (int i = 0; i < 4; ++i) {
    float mx = -1e30f;
    #pragma unroll
    for (int j = 0; j < 4; ++j) {
      const int s = tx * 4 + j;
      float v = (s < scnt) ? acc[i][j] * SCALE_ATT : -1e30f;
      acc[i][j] = v;
      mx = fmaxf(mx, v);
    }
    #pragma unroll
    for (int off = 1; off < 16; off <<= 1) mx = fmaxf(mx, __shfl_xor(mx, off, 16));
    float sum = 0.f;
    #pragma unroll
    for (int j = 0; j < 4; ++j) {
      const float p = __expf(acc[i][j] - mx);
      acc[i][j] = p;
      sum += p;
    }
    #pragma unroll
    for (int off = 1; off < 16; off <<= 1) sum += __shfl_xor(sum, off, 16);
    #pragma unroll
    for (int j = 0; j < 4; ++j)
      p_t[(tx * 4 + j) * 68 + ty * 4 + i] = acc[i][j];
    if (tx == 0) {
      const size_t mb = (((size_t)b * NSC + chunk) * NQ + ty * 4 + i) * 2;
      ml[mb] = mx; ml[mb + 1] = sum;
    }
  }

  // ---- step C: o_lat partial = P . c_kv, dbuf LDS + async-stage split; bf16 output
  const int sl = tid >> 3;          // 0..31
  const int c16 = (tid & 7) * 16;
  float4 rc0, rc1, rc2, rc3;
  auto loadC = [&](int step) {
    const int rq = step >> 1, sck = step & 1;
    const int s = sck * 32 + sl;
    if (s < scnt) {
      const float4* s4 = reinterpret_cast<const float4*>(ckv + (size_t)s * RANKC + rq * 128 + c16);
      rc0 = s4[0]; rc1 = s4[1]; rc2 = s4[2]; rc3 = s4[3];
    } else { rc0 = make_float4(0.f, 0.f, 0.f, 0.f); rc1 = rc0; rc2 = rc0; rc3 = rc0; }
  };
  auto writeC = [&](float* dst) {
    float4* d4 = reinterpret_cast<float4*>(&dst[sl * 136 + c16]);
    d4[0] = rc0; d4[1] = rc1; d4[2] = rc2; d4[3] = rc3;
  };
  loadC(0);
  writeC(CS0);
  __syncthreads();                  // covers p_t writes + CS0
  const size_t obase = ((size_t)b * NSC + chunk) * NQ * RANKC;
  float acc2[4][8];
  for (int step = 0; step < 8; ++step) {
    if (step < 7) loadC(step + 1);  // issue early
    const float* cs = (step & 1) ? CS1 : CS0;
    const int rq = step >> 1, sck = step & 1;
    if (sck == 0) {
      #pragma unroll
      for (int i = 0; i < 4; ++i)
        #pragma unroll
        for (int j = 0; j < 8; ++j) acc2[i][j] = 0.f;
    }
    #pragma unroll 8
    for (int ss = 0; ss < 32; ++ss) {
      const float4 pv = *reinterpret_cast<const float4*>(&p_t[(sck * 32 + ss) * 68 + ty * 4]);
      const float4 c0 = *reinterpret_cast<const float4*>(&cs[ss * 136 + tx * 4]);
      const float4 c1 = *reinterpret_cast<const float4*>(&cs[ss * 136 + 64 + tx * 4]);
      const float p_[4] = {pv.x, pv.y, pv.z, pv.w};
      const float cv[8] = {c0.x, c0.y, c0.z, c0.w, c1.x, c1.y, c1.z, c1.w};
      #pragma unroll
      for (int i = 0; i < 4; ++i)
        #pragma unroll
        for (int j = 0; j < 8; ++j)
          acc2[i][j] = fmaf(p_[i], cv[j], acc2[i][j]);
    }
    if (step < 7) writeC((step & 1) ? CS0 : CS1);   // write late
    if (sck == 1) {
      #pragma unroll
      for (int i = 0; i < 4; ++i) {
        const size_t rbase = obase + (size_t)(ty * 4 + i) * RANKC + rq * 128;
        uint2 w0 = make_uint2(pk2(acc2[i][0], acc2[i][1]), pk2(acc2[i][2], acc2[i][3]));
        uint2 w1 = make_uint2(pk2(acc2[i][4], acc2[i][5]), pk2(acc2[i][6], acc2[i][7]));
        *reinterpret_cast<uint2*>(&olat[rbase + tx * 4])      = w0;
        *reinterpret_cast<uint2*>(&olat[rbase + 64 + tx * 4]) = w1;
      }
    }
    __syncthreads();
  }
}

// ---------------- fused combine + out_head epilogue (olat partials are bf16)
// grid (16 h, 8 b), 512 threads
__global__ __launch_bounds__(512) void k_combF(const float* __restrict__ ml,
                                               const unsigned short* __restrict__ olat,
                                               const float* __restrict__ wup,
                                               float* __restrict__ ohead) {
  __shared__ float wrow[4][66];
  __shared__ float att_lds[4][516];
  const int h = blockIdx.x, b = blockIdx.y;
  const int tid = threadIdx.x;
  const int wave = tid >> 6;
  const int i = wave >> 1;          // t
  const int rhalf = wave & 1;
  const int rl = tid & 63;
  const int qi = h * TT + i;
  float m1 = -1e30f, l1 = 0.f, m2 = -1e30f, l2 = 0.f;
  {
    const size_t base = (((size_t)b * NSC + rl) * NQ + qi) * 2;
    m1 = ml[base]; l1 = ml[base + 1];
    if (rl == 0) {
      const size_t b2 = (((size_t)b * NSC + 64) * NQ + qi) * 2;
      m2 = ml[b2]; l2 = ml[b2 + 1];
    }
  }
  float M = fmaxf(m1, m2);
  #pragma unroll
  for (int off = 1; off < 64; off <<= 1) M = fmaxf(M, __shfl_xor(M, off));
  float L = l1 * __expf(m1 - M) + ((rl == 0) ? l2 * __expf(m2 - M) : 0.f);
  #pragma unroll
  for (int off = 1; off < 64; off <<= 1) L += __shfl_xor(L, off);
  const float invL = 1.0f / L;
  wrow[i][rl] = __expf(m1 - M) * invL;
  if (rl == 0) wrow[i][64] = __expf(m2 - M) * invL;
  __syncthreads();
  const int r0 = rhalf * 256 + rl * 4;
  float o0 = 0.f, o1 = 0.f, o2 = 0.f, o3 = 0.f;
  for (int c = 0; c < NSC; ++c) {
    const float w = wrow[i][c];
    const uint2 v = *reinterpret_cast<const uint2*>(
        olat + (((size_t)b * NSC + c) * NQ + qi) * RANKC + r0);
    o0 = fmaf(bf2f(v.x & 0xffffu), w, o0);
    o1 = fmaf(bf2f(v.x >> 16), w, o1);
    o2 = fmaf(bf2f(v.y & 0xffffu), w, o2);
    o3 = fmaf(bf2f(v.y >> 16), w, o3);
  }
  *reinterpret_cast<float4*>(&att_lds[i][r0]) = make_float4(o0, o1, o2, o3);
  __syncthreads();
  const int col = tid & 127;
  const int t = tid >> 7;
  float acc = 0.f;
  #pragma unroll 8
  for (int r = 0; r < RANKC; ++r)
    acc = fmaf(att_lds[t][r], wup[(size_t)r * HD + h * DDIM + col], acc);
  ohead[(size_t)(b * TT + t) * HD + h * DDIM + col] = acc;
}

extern "C" void kernel_launch(void* const* d_in, const int* in_sizes, int n_in,
                              void* d_out, int out_size, void* d_ws, size_t ws_size,
                              hipStream_t stream) {
  const float* x     = (const float*)d_in[0];
  const float* cckv  = (const float*)d_in[1];
  const float* ckr   = (const float*)d_in[2];
  const float* w_q   = (const float*)d_in[3];
  const float* w_qr  = (const float*)d_in[4];
  const float* w_kvd = (const float*)d_in[5];
  const float* w_kvu = (const float*)d_in[6];
  const float* w_kr  = (const float*)d_in[7];
  const float* w_out = (const float*)d_in[8];
  float* out = (float*)d_out;
  float* ws = (float*)d_ws;

  size_t off = 0;
  float* act   = ws + off; off += 32ull * NACT;                  // 114688
  float* qlat  = ws + off; off += (size_t)BB * NQ * RANKC;       // 262144
  float* qrope = ws + off; off += (size_t)BB * NQ * RRDIM;       // 32768
  float* ckvn  = ws + off; off += (size_t)BB * TT * RANKC;       // 16384
  float* krn   = ws + off; off += (size_t)BB * TT * HH * RRDIM;  // 32768
  float* mlb   = ws + off; off += (size_t)BB * NSC * NQ * 2;     // 66560
  float* ohead = ws + off; off += 32ull * HD;                    // 65536
  float* rsb   = ws + off; off += 512ull * SPAD;                 // 2129920
  // region B (time-shared): part0 -> olat(bf16) -> part3; max = olat 8519680 float-slots
  float* regB  = ws + off;
  float* part0 = regB;
  unsigned short* olat = (unsigned short*)regB;                  // 17039360 bf16
  float* part3 = regB;

  k_proj4<<<dim3(28, 16), 256, 0, stream>>>(x, w_q, w_qr, w_kvd, w_kr, part0);
  k_reduce<<<dim3(448), 256, 0, stream>>>(part0, act, 32 * NACT, 16);
  k_qlatrope<<<dim3(256), 256, 0, stream>>>(act, w_kvu, qlat, qrope, ckvn, krn);
  k_rscore<<<dim3(128, 9), 256, 0, stream>>>(ckr, krn, qrope, rsb);

  k_attn<<<dim3(BB, NSC), 256, 0, stream>>>(cckv, ckvn, rsb, qlat, mlb, olat);

  k_combF<<<dim3(16, 8), 512, 0, stream>>>(mlb, olat, w_kvu, ohead);
  k_proj<<<dim3(16, 16), 256, 0, stream>>>(ohead, w_out, part3, 2048, 2048, 0);
  k_reduce<<<dim3(256), 256, 0, stream>>>(part3, out, 32 * HD, 16);
}